// Round 12
// baseline (854.507 us; speedup 1.0000x reference)
//
#include <hip/hip_runtime.h>

#define N_NODES 10000
#define N_EDGES 50000
#define IN0     32
#define EDGE_IN 16
#define GIN     8
#define HID     64
#define NG      64
#define KDIM    128
#define BV      16        // virtual nodes per fused block
#define NVMAX   12500     // sum ceil(deg/16) <= (E + 15*N)/16
#define EPS     1e-5f

typedef _Float16 f16;
typedef _Float16 v8h __attribute__((ext_vector_type(8)));
typedef float    v4f __attribute__((ext_vector_type(4)));

#define HTSTR ((size_t)N_EDGES * KDIM)      // per-layer htp stride (f16)
#define BGSTR ((size_t)8256 * 64)           // per-layer Bg2 stride (f16)

// ---------------------------------------------------------------------------
// ALL 4 LAYERS in one dispatch (blockIdx.y = layer). htp[l][einv[e]][j] =
// f16(relu(ea[e]@w1_l[:,j] + b1_l[j])), rows permuted into src-CSR order.
// Hot loop reads: ea from REGISTERS, w1/b1 from LDS (wave-uniform broadcast) --
// no SMEM/per-lane-LDS in the inner loop (R11's 119us was lgkmcnt serialization).
__global__ __launch_bounds__(256) void ht_kernel(const float* __restrict__ ea,
                                                 const float* __restrict__ e0w1,
                                                 const float* __restrict__ e0b1,
                                                 const float* __restrict__ ew1,
                                                 const float* __restrict__ eb1,
                                                 const int* __restrict__ einv,
                                                 f16* __restrict__ htp) {
    const int l = blockIdx.y;
    const float* w1 = (l == 0) ? e0w1 : ew1 + (size_t)(l - 1) * EDGE_IN * KDIM;
    const float* b1 = (l == 0) ? e0b1 : eb1 + (size_t)(l - 1) * KDIM;
    f16* out = htp + (size_t)l * HTSTR;

    __shared__ float w1s[EDGE_IN][KDIM + 1];   // 8.3 KB
    __shared__ float b1s[KDIM];                // 0.5 KB
    __shared__ float eas[128][17];             // 8.7 KB
    __shared__ f16 hl[128][136];               // 34.8 KB  (total ~52 KB -> 3 blk/CU)
    const int e0 = blockIdx.x * 128, t = threadIdx.x;
    for (int idx = t; idx < EDGE_IN * KDIM; idx += 256)
        w1s[idx >> 7][idx & 127] = w1[idx];
    if (t < KDIM) b1s[t] = b1[t];
    for (int idx = t; idx < 128 * 16; idx += 256) {
        int r = idx >> 4, i = idx & 15;
        eas[r][i] = (e0 + r < N_EDGES) ? ea[(size_t)(e0 + r) * EDGE_IN + i] : 0.f;
    }
    __syncthreads();
    const int el = t & 127, jh = t >> 7;
    float ear[EDGE_IN];
#pragma unroll
    for (int i = 0; i < EDGE_IN; i++) ear[i] = eas[el][i];
#pragma unroll 4
    for (int jj = 0; jj < 64; jj++) {
        const int j = jh * 64 + jj;
        float a0 = b1s[j], a1 = 0.f;
#pragma unroll
        for (int i = 0; i < EDGE_IN; i += 2) {
            a0 += ear[i]     * w1s[i][j];
            a1 += ear[i + 1] * w1s[i + 1][j];
        }
        hl[el][j] = (f16)fmaxf(a0 + a1, 0.f);
    }
    __syncthreads();
    for (int idx = t; idx < 128 * 16; idx += 256) {     // 16 uint4 per 128-f16 row
        const int row = idx >> 4, sg = idx & 15;
        if (e0 + row < N_EDGES) {
            uint4* dp = (uint4*)(out + (size_t)einv[e0 + row] * KDIM) + sg;
            *dp = *((const uint4*)(&hl[row][0]) + sg);
        }
    }
}

// ---------------------------------------------------------------------------
// xf[idx] = f16(x[idx])   (layer 0 input only; later layers get xf from bn_apply)
__global__ __launch_bounds__(256) void xconv(const float* __restrict__ x,
                                             f16* __restrict__ xf, int n) {
    int idx = blockIdx.x * 256 + threadIdx.x;
    if (idx < n) xf[idx] = (f16)x[idx];
}

// ---------------------------------------------------------------------------
// ALL 4 LAYERS in one dispatch (blockIdx.y = layer).
// Bg2[l][C'][i], C' = o*128 + k (k minor) for k<128: w2_l[k][i*64+o];
// rows 8192+o: b2_l[i*64+o] (the per-node bias term ub). f16.
__global__ __launch_bounds__(256) void bconv(const float* __restrict__ e0w2,
                                             const float* __restrict__ e0b2,
                                             const float* __restrict__ ew2,
                                             const float* __restrict__ eb2,
                                             f16* __restrict__ Bg2all) {
    const int l = blockIdx.y;
    const int inshift = l ? 6 : 5;
    const int in = 1 << inshift;
    const float* w2 = (l == 0) ? e0w2 : ew2 + (size_t)(l - 1) * KDIM * HID * HID;
    const float* b2 = (l == 0) ? e0b2 : eb2 + (size_t)(l - 1) * HID * HID;
    f16* Bg2 = Bg2all + (size_t)l * BGSTR;

    const int total = 8256 << inshift;
    int idx = blockIdx.x * 256 + threadIdx.x;
    if (idx >= total) return;
    const int i = idx & (in - 1), C = idx >> inshift;
    float v;
    if (C < 8192) {
        const int k = C & 127, o = C >> 7;
        v = w2[(size_t)k * (in << 6) + (i << 6) + o];
    } else {
        const int o = C - 8192;
        v = b2[(i << 6) + o];
    }
    Bg2[idx] = (f16)v;
}

// ---------------------------------------------------------------------------
// CSR over SRC (constant across layers; built once) + virtual-node list:
// vnode = (node, 16-edge subrange). nv <= NVMAX.
__global__ __launch_bounds__(256) void csr_count(const int* __restrict__ src,
                                                 int* __restrict__ cnt) {
    int e = blockIdx.x * 256 + threadIdx.x;
    if (e < N_EDGES) atomicAdd(&cnt[src[e]], 1);
}

__global__ __launch_bounds__(256) void csr_scan(const int* __restrict__ cnt,
                                                int* __restrict__ row_ptr,
                                                int* __restrict__ cursor,
                                                int* __restrict__ vn_node,
                                                int* __restrict__ vn_rb,
                                                int* __restrict__ nvp) {
    __shared__ int part[256], psum[257];
    __shared__ int vpart[256], vpsum[257];
    const int t = threadIdx.x;
    const int base = t * 40;                       // 256*40 >= 10000
    int s = 0, vs = 0;
    for (int i = 0; i < 40; i++) {
        int idx = base + i;
        if (idx < N_NODES) { int d = cnt[idx]; s += d; vs += (d + 15) >> 4; }
    }
    part[t] = s; vpart[t] = vs;
    __syncthreads();
    if (t == 0) {
        int run = 0, vrun = 0;
        for (int i = 0; i < 256; i++) {
            psum[i] = run;  run += part[i];
            vpsum[i] = vrun; vrun += vpart[i];
        }
        psum[256] = run; vpsum[256] = vrun;
    }
    __syncthreads();
    int run = psum[t], vrun = vpsum[t];
    for (int i = 0; i < 40; i++) {
        int idx = base + i;
        if (idx < N_NODES) {
            int d = cnt[idx];
            row_ptr[idx] = run; cursor[idx] = run;
            int nvn = (d + 15) >> 4;
            for (int j = 0; j < nvn; j++) {
                vn_node[vrun] = idx; vn_rb[vrun] = run + j * 16; vrun++;
            }
            run += d;
        }
    }
    if (t == 255) { row_ptr[N_NODES] = psum[256]; *nvp = vpsum[256]; }
}

__global__ __launch_bounds__(256) void csr_fill(const int* __restrict__ src,
                                                int* __restrict__ cursor,
                                                int* __restrict__ eix,
                                                int* __restrict__ einv) {
    int e = blockIdx.x * 256 + threadIdx.x;
    if (e < N_EDGES) {
        int p = atomicAdd(&cursor[src[e]], 1);
        eix[p] = e;
        einv[e] = p;
    }
}

// ---------------------------------------------------------------------------
// Node-factored NNConv, DOUBLE-BUFFERED tcs (T(c+1) overlaps app(c) in one
// barrier interval => 8 barriers instead of 16, T-load chain and app-MFMA
// chain are independent => in-wave ILP). Per-buffer indexing byte-identical
// to the R10/R11 passing kernel.
//   T[n,k,o] = sum_i xf[n,i] * w2[k,i,o]
//   msg[e,o] = sum_k ht[e,k] * T[src,k,o] + ub[src,o];  agg[dst] += msg
__global__ __launch_bounds__(256, 1) void fused_msg2(const f16* __restrict__ htp,
                                                     const f16* __restrict__ xf,
                                                     const f16* __restrict__ Bg2,
                                                     const int* __restrict__ eix,
                                                     const int* __restrict__ row_ptr,
                                                     const int* __restrict__ vn_node,
                                                     const int* __restrict__ vn_rb,
                                                     const int* __restrict__ dst,
                                                     float* __restrict__ agg,
                                                     const int* __restrict__ nvp,
                                                     int inshift) {
    __shared__ f16 tcs[2][BV * 1024 + 32];  // 2 x ([slot][(o^(slot&3))][k16] + pad)
    __shared__ f16 ubs[BV * 68];            // [slot][o] row-padded 64->68
    __shared__ int snd[BV], srb[BV], sct[BV];

    const int t = threadIdx.x;
    const int w = t >> 6, lane = t & 63;
    const int m = lane & 15, q = lane >> 4;
    const int v0 = blockIdx.x * BV;
    const int nv = *nvp;
    if (v0 >= nv) return;
    const bool in64 = (inshift == 6);

    for (int i = t; i < BV; i += 256) {
        int v = v0 + i, n = 0, rb = 0, ct = 0;
        if (v < nv) {
            n = vn_node[v]; rb = vn_rb[v];
            int re = row_ptr[n + 1];
            ct = re - rb; if (ct > 16) ct = 16;
        }
        snd[i] = n; srb[i] = rb; sct[i] = ct;
    }
    // zero both buffers' tail pads (vn=BV-1, q>=2 lanes read them with zero-A;
    // stale NaN would poison 0*x)
    if (t < 16) *(uint2*)(tcs[t >> 3] + BV * 1024 + (t & 7) * 4) = (uint2){0u, 0u};
    __syncthreads();

    // T-phase B-fragment: xf row of slot m (N dim = the 16 slots)
    v8h bfx[2];
    {
        const size_t nb = (size_t)snd[m] << inshift;
        bfx[0] = *(const v8h*)(xf + nb + q * 8);
        if (in64) bfx[1] = *(const v8h*)(xf + nb + 32 + q * 8);
    }

    // chunk-invariant htp row pointer per j (this lane's edge slot of vnode)
    const f16* hrow[4];
#pragma unroll
    for (int j = 0; j < 4; j++) {
        const int vn = (w << 2) + j;
        const int rb = srb[vn], ct = sct[vn];
        const int es = (m < ct) ? m : (ct > 0 ? ct - 1 : 0);
        hrow[j] = htp + (size_t)(rb + es) * KDIM;
    }

    // T-phase for chunk c into buffer tbuf (indexing identical to R10/R11)
    auto t_phase = [&](int c, f16* tbuf) {
#pragma unroll 4
        for (int ol = 0; ol < 16; ol++) {
            const int o = (w << 4) + ol;
            const size_t arow = ((size_t)(o * 128 + (c << 4) + m)) << inshift;
            v8h a0 = *(const v8h*)(Bg2 + arow + q * 8);
            v8h a1;
            if (in64) a1 = *(const v8h*)(Bg2 + arow + 32 + q * 8);
            v4f d = (v4f){0.f, 0.f, 0.f, 0.f};
            d = __builtin_amdgcn_mfma_f32_16x16x32_f16(a0, bfx[0], d, 0, 0, 0);
            if (in64)
                d = __builtin_amdgcn_mfma_f32_16x16x32_f16(a1, bfx[1], d, 0, 0, 0);
            union { f16 x[4]; uint2 u; } pk;
            pk.x[0] = (f16)d[0]; pk.x[1] = (f16)d[1];
            pk.x[2] = (f16)d[2]; pk.x[3] = (f16)d[3];
            *(uint2*)(tbuf + m * 1024 + ((o ^ (m & 3)) << 4) + (q << 2)) = pk.u;
        }
    };
    auto load_h = [&](int c, v8h* hp) {
#pragma unroll
        for (int j = 0; j < 4; j++) {
            v8h tmp;
#pragma unroll
            for (int z = 0; z < 8; z++) tmp[z] = (f16)0.f;
            if (q < 2)      // lanes q>=2 are k 16..31 of the MFMA: zero (K=16 pad)
                tmp = *(const v8h*)(hrow[j] + (c << 4) + q * 8);
            hp[j] = tmp;
        }
    };

    v4f acc[4][4];
#pragma unroll
    for (int j = 0; j < 4; j++)
#pragma unroll
        for (int ot = 0; ot < 4; ot++) acc[j][ot] = (v4f){0.f, 0.f, 0.f, 0.f};

    v8h hpre[4], hnext[4];
    load_h(0, hpre);
    t_phase(0, tcs[0]);
    __syncthreads();

    for (int c = 0; c < 8; c++) {
        f16* tcur = tcs[c & 1];
        if (c < 7) {
            load_h(c + 1, hnext);            // HBM/L2 latency hides under MFMAs
            t_phase(c + 1, tcs[(c + 1) & 1]);
        }
        // app-phase: wave w applies vnode slots w*4 .. w*4+3 from tcur
#pragma unroll
        for (int j = 0; j < 4; j++) {
            const int vn = (w << 2) + j;
            const f16* tb = tcur + vn * 1024;
            const int nx = vn & 3;
#pragma unroll
            for (int ot = 0; ot < 4; ot++) {
                v8h hb = *(const v8h*)(tb + ((((ot << 4) + m) ^ nx) << 4) + (q << 3));
                acc[j][ot] = __builtin_amdgcn_mfma_f32_16x16x32_f16(hpre[j], hb,
                                                                    acc[j][ot], 0, 0, 0);
            }
        }
        __syncthreads();
        if (c < 7) {
#pragma unroll
            for (int j = 0; j < 4; j++) hpre[j] = hnext[j];
        }
    }

    // ---- ub mini-chunk: ub[slot][o] = sum_i xf[n,i] b2[i,o] (Bg2 rows 8192+o)
    {
        const size_t arow = ((size_t)(8192 + (w << 4) + m)) << inshift;
        v8h a0 = *(const v8h*)(Bg2 + arow + q * 8);
        v4f d = (v4f){0.f, 0.f, 0.f, 0.f};
        d = __builtin_amdgcn_mfma_f32_16x16x32_f16(a0, bfx[0], d, 0, 0, 0);
        if (in64) {
            v8h a1 = *(const v8h*)(Bg2 + arow + 32 + q * 8);
            d = __builtin_amdgcn_mfma_f32_16x16x32_f16(a1, bfx[1], d, 0, 0, 0);
        }
        union { f16 x[4]; uint2 u; } pk;
        pk.x[0] = (f16)d[0]; pk.x[1] = (f16)d[1];
        pk.x[2] = (f16)d[2]; pk.x[3] = (f16)d[3];
        *(uint2*)(ubs + m * 68 + (w << 4) + (q << 2)) = pk.u;
    }
    __syncthreads();

    // ---- epilogue: scatter acc + ub into agg by dst (f32 atomics)
#pragma unroll
    for (int j = 0; j < 4; j++) {
        const int vn = (w << 2) + j;
        const int rb = srb[vn], ct = sct[vn];
        if (ct == 0) continue;                        // wave-uniform
        int dr[4];
#pragma unroll
        for (int r = 0; r < 4; r++) {
            const int es = (q << 2) + r;
            dr[r] = (es < ct) ? dst[eix[rb + es]] : -1;
        }
#pragma unroll
        for (int ot = 0; ot < 4; ot++) {
            const float ub = (float)ubs[vn * 68 + (ot << 4) + m];
#pragma unroll
            for (int r = 0; r < 4; r++)
                if (dr[r] >= 0)
                    atomicAdd(&agg[(size_t)dr[r] * 64 + (ot << 4) + m],
                              acc[j][ot][r] + ub);
        }
    }
}

// ---------------------------------------------------------------------------
// pre[n,o] = agg[n,o] + sum_i x[n,i]*root[i,o] + bias[o]; accumulate BN stats.
__global__ __launch_bounds__(256) void pre_stats(const float* __restrict__ agg,
                                                 const float* __restrict__ x,
                                                 const float* __restrict__ root,
                                                 const float* __restrict__ bias,
                                                 float* __restrict__ pre,
                                                 float* __restrict__ stats,
                                                 int in, int inshift) {
    __shared__ float xs[4][64];
    __shared__ float lsum[64], lsq[64];
    const int o = threadIdx.x & 63, nl = threadIdx.x >> 6;
    if (threadIdx.x < 64) { lsum[threadIdx.x] = 0.f; lsq[threadIdx.x] = 0.f; }
    const float bo = bias[o];
    for (int n0 = blockIdx.x * 4; n0 < N_NODES; n0 += gridDim.x * 4) {
        __syncthreads();
        for (int idx = threadIdx.x; idx < (4 << inshift); idx += 256) {
            int r = idx >> inshift, i = idx & (in - 1);
            if (n0 + r < N_NODES) xs[r][i] = x[(size_t)(n0 + r) * in + i];
        }
        __syncthreads();
        int n = n0 + nl;
        if (n < N_NODES) {
            float acc = agg[(size_t)n * 64 + o] + bo;
#pragma unroll 8
            for (int i = 0; i < in; i++) acc += xs[nl][i] * root[i * 64 + o];
            pre[(size_t)n * 64 + o] = acc;
            atomicAdd(&lsum[o], acc);
            atomicAdd(&lsq[o], acc * acc);
        }
    }
    __syncthreads();
    if (threadIdx.x < 64) {
        atomicAdd(&stats[threadIdx.x], lsum[threadIdx.x]);
        atomicAdd(&stats[64 + threadIdx.x], lsq[threadIdx.x]);
    }
}

// ---------------------------------------------------------------------------
// BN (batch stats, biased var) + ReLU. Zeroes pre(=agg) after its single read
// (replaces the per-layer agg memset). mode 0: store xn (f32) + xf (f16, input
// to next layer's fused T-phase). mode 1: segment-max pool.
__global__ __launch_bounds__(256) void bn_apply(float* __restrict__ pre,
                                                const float* __restrict__ stats,
                                                const float* __restrict__ gamma,
                                                const float* __restrict__ beta,
                                                float* __restrict__ xn,
                                                f16* __restrict__ xfo,
                                                const int* __restrict__ batch,
                                                float* __restrict__ pooled,
                                                int mode) {
    int idx = blockIdx.x * 256 + threadIdx.x;
    if (idx >= N_NODES * 64) return;
    const int o = idx & 63, n = idx >> 6;
    const float inv = 1.f / (float)N_NODES;
    float mu = stats[o] * inv;
    float var = stats[64 + o] * inv - mu * mu;
    float sc = gamma[o] * rsqrtf(var + EPS);
    float sh = beta[o] - mu * sc;
    float p = pre[idx];
    pre[idx] = 0.f;                     // agg zeroed for the next layer's fused
    float v = fmaxf(p * sc + sh, 0.f);
    if (mode == 0) { xn[idx] = v; xfo[idx] = (f16)v; }
    else atomicMax((int*)&pooled[(size_t)batch[n] * 64 + o], __float_as_int(v));
}

// ---------------------------------------------------------------------------
// out[g] = pp_b2 + relu(cat(pooled[g],u[g]) @ pp_w1 + pp_b1) @ pp_w2
__global__ __launch_bounds__(64) void final_mlp(const float* __restrict__ pooled,
                                                const float* __restrict__ u,
                                                const float* __restrict__ w1,
                                                const float* __restrict__ b1,
                                                const float* __restrict__ w2,
                                                const float* __restrict__ b2,
                                                float* __restrict__ out) {
    const int g = blockIdx.x, t = threadIdx.x;
    float acc = b1[t];
#pragma unroll 8
    for (int i = 0; i < 64; i++) acc += pooled[g * 64 + i] * w1[i * 64 + t];
#pragma unroll
    for (int j = 0; j < GIN; j++) acc += u[g * GIN + j] * w1[(64 + j) * 64 + t];
    float hv = fmaxf(acc, 0.f) * w2[t];
#pragma unroll
    for (int off = 32; off > 0; off >>= 1) hv += __shfl_down(hv, off, 64);
    if (t == 0) out[g] = hv + b2[0];
}

// ---------------------------------------------------------------------------
extern "C" void kernel_launch(void* const* d_in, const int* in_sizes, int n_in,
                              void* d_out, int out_size, void* d_ws, size_t ws_size,
                              hipStream_t stream) {
    const float* x0      = (const float*)d_in[0];
    const int*   ei      = (const int*)d_in[1];
    const int*   src     = ei;
    const int*   dst     = ei + N_EDGES;
    const float* ea      = (const float*)d_in[2];
    const int*   batch   = (const int*)d_in[3];
    const float* u       = (const float*)d_in[4];
    const float* e0w1    = (const float*)d_in[5];
    const float* e0b1    = (const float*)d_in[6];
    const float* e0w2    = (const float*)d_in[7];
    const float* e0b2    = (const float*)d_in[8];
    const float* root0   = (const float*)d_in[9];
    const float* bias0   = (const float*)d_in[10];
    const float* gamma0  = (const float*)d_in[11];
    const float* beta0   = (const float*)d_in[12];
    const float* ew1     = (const float*)d_in[13];
    const float* eb1     = (const float*)d_in[14];
    const float* ew2     = (const float*)d_in[15];
    const float* eb2     = (const float*)d_in[16];
    const float* rootl   = (const float*)d_in[17];
    const float* biasl   = (const float*)d_in[18];
    const float* gammal  = (const float*)d_in[19];
    const float* betal   = (const float*)d_in[20];
    const float* pp_w1   = (const float*)d_in[21];
    const float* pp_b1   = (const float*)d_in[22];
    const float* pp_w2   = (const float*)d_in[23];
    const float* pp_b2   = (const float*)d_in[24];

    float* ws = (float*)d_ws;
    size_t off = 0;
    f16*   htp    = (f16*)(ws + off); off += 4 * HTSTR / 2;        // 51.2 MB
    f16*   xf     = (f16*)(ws + off); off += (size_t)N_NODES * 64 / 2;
    f16*   Bg2    = (f16*)(ws + off); off += 4 * BGSTR / 2;        // 4.2 MB
    float* agg    = ws + off; off += (size_t)N_NODES * 64;
    float* xa     = ws + off; off += (size_t)N_NODES * 64;
    float* xb     = ws + off; off += (size_t)N_NODES * 64;
    float* stats  = ws + off; off += 4 * 128 + 64;
    float* pooled = ws + off; off += (size_t)NG * 64;
    int*   row_ptr = (int*)(ws + off); off += 10008;
    int*   cursor  = (int*)(ws + off); off += 10000;
    int*   cnt     = (int*)(ws + off); off += 10000;
    int*   eix     = (int*)(ws + off); off += N_EDGES;
    int*   einv    = (int*)(ws + off); off += N_EDGES;
    int*   vn_node = (int*)(ws + off); off += NVMAX + 12;
    int*   vn_rb   = (int*)(ws + off); off += NVMAX + 12;
    int*   nvp     = (int*)(ws + off); off += 8;

    const int eblocks = (N_EDGES + 255) / 256;               // 196
    const int hblocks = (N_EDGES + 127) / 128;               // 391
    const int bblocks = ((8256 << 6) + 255) / 256;           // 2064
    const int fblocks = (NVMAX + BV - 1) / BV;               // 782
    const int ablocks = (N_NODES * 64 + 255) / 256;

    // ---- head: layer-independent work, once
    hipMemsetAsync(pooled, 0, (size_t)NG * 64 * 4, stream);
    hipMemsetAsync(agg, 0, (size_t)N_NODES * 64 * 4, stream);
    hipMemsetAsync(stats, 0, 4 * 128 * 4, stream);
    hipMemsetAsync(cnt, 0, N_NODES * 4, stream);
    csr_count<<<eblocks, 256, 0, stream>>>(src, cnt);
    csr_scan<<<1, 256, 0, stream>>>(cnt, row_ptr, cursor, vn_node, vn_rb, nvp);
    csr_fill<<<eblocks, 256, 0, stream>>>(src, cursor, eix, einv);
    ht_kernel<<<dim3(hblocks, 4), 256, 0, stream>>>(ea, e0w1, e0b1, ew1, eb1,
                                                    einv, htp);
    bconv<<<dim3(bblocks, 4), 256, 0, stream>>>(e0w2, e0b2, ew2, eb2, Bg2);
    xconv<<<(N_NODES * IN0 + 255) / 256, 256, 0, stream>>>(x0, xf, N_NODES * IN0);

    struct Layer {
        const float *root, *bias, *gamma, *beta, *xin;
        float* xout; int in, inshift, mode;
    };
    Layer L[4];
    L[0] = {root0, bias0, gamma0, beta0, x0, xa, IN0, 5, 0};
    for (int l = 0; l < 3; l++) {
        const float* xin  = (l == 0) ? xa : ((l == 1) ? xb : xa);
        float*       xout = (l == 0) ? xb : ((l == 1) ? xa : nullptr);
        L[l + 1] = {rootl + (size_t)l * HID * HID, biasl + (size_t)l * HID,
                    gammal + (size_t)l * HID, betal + (size_t)l * HID,
                    xin, xout, HID, 6, (l == 2) ? 1 : 0};
    }

    // ---- per-layer critical path: fused -> pre_stats -> bn_apply
    for (int l = 0; l < 4; l++) {
        const Layer& P = L[l];
        fused_msg2<<<fblocks, 256, 0, stream>>>(htp + (size_t)l * HTSTR, xf,
                                                Bg2 + (size_t)l * BGSTR, eix,
                                                row_ptr, vn_node, vn_rb, dst,
                                                agg, nvp, P.inshift);
        pre_stats<<<512, 256, 0, stream>>>(agg, P.xin, P.root, P.bias, agg,
                                           stats + l * 128, P.in, P.inshift);
        bn_apply<<<ablocks, 256, 0, stream>>>(agg, stats + l * 128, P.gamma,
                                              P.beta, P.xout, xf, batch, pooled,
                                              P.mode);
    }
    final_mlp<<<NG, 64, 0, stream>>>(pooled, u, pp_w1, pp_b1, pp_w2, pp_b2,
                                     (float*)d_out);
}

// Round 13
// 746.847 us; speedup vs baseline: 1.1442x; 1.1442x over previous
//
#include <hip/hip_runtime.h>

#define N_NODES 10000
#define N_EDGES 50000
#define IN0     32
#define EDGE_IN 16
#define GIN     8
#define HID     64
#define NG      64
#define KDIM    128
#define BV      16        // virtual nodes per fused block
#define NVMAX   12500     // sum ceil(deg/16) <= (E + 15*N)/16
#define EPS     1e-5f

typedef _Float16 f16;
typedef _Float16 v8h __attribute__((ext_vector_type(8)));
typedef float    v4f __attribute__((ext_vector_type(4)));

#define HTSTR ((size_t)N_EDGES * KDIM)      // per-layer htp stride (f16)
#define BGSTR ((size_t)8256 * 64)           // per-layer Bg2 stride (f16)

// ---------------------------------------------------------------------------
// ALL 4 LAYERS in one dispatch (blockIdx.y = layer). htp[l][einv[e]][j] =
// f16(relu(ea[e]@w1_l[:,j] + b1_l[j])), rows permuted into src-CSR order.
// Hot loop reads: ea from REGISTERS, w1/b1 from LDS (wave-uniform broadcast).
__global__ __launch_bounds__(256) void ht_kernel(const float* __restrict__ ea,
                                                 const float* __restrict__ e0w1,
                                                 const float* __restrict__ e0b1,
                                                 const float* __restrict__ ew1,
                                                 const float* __restrict__ eb1,
                                                 const int* __restrict__ einv,
                                                 f16* __restrict__ htp) {
    const int l = blockIdx.y;
    const float* w1 = (l == 0) ? e0w1 : ew1 + (size_t)(l - 1) * EDGE_IN * KDIM;
    const float* b1 = (l == 0) ? e0b1 : eb1 + (size_t)(l - 1) * KDIM;
    f16* out = htp + (size_t)l * HTSTR;

    __shared__ float w1s[EDGE_IN][KDIM + 1];   // 8.3 KB
    __shared__ float b1s[KDIM];                // 0.5 KB
    __shared__ float eas[128][17];             // 8.7 KB
    __shared__ f16 hl[128][136];               // 34.8 KB
    const int e0 = blockIdx.x * 128, t = threadIdx.x;
    for (int idx = t; idx < EDGE_IN * KDIM; idx += 256)
        w1s[idx >> 7][idx & 127] = w1[idx];
    if (t < KDIM) b1s[t] = b1[t];
    for (int idx = t; idx < 128 * 16; idx += 256) {
        int r = idx >> 4, i = idx & 15;
        eas[r][i] = (e0 + r < N_EDGES) ? ea[(size_t)(e0 + r) * EDGE_IN + i] : 0.f;
    }
    __syncthreads();
    const int el = t & 127, jh = t >> 7;
    float ear[EDGE_IN];
#pragma unroll
    for (int i = 0; i < EDGE_IN; i++) ear[i] = eas[el][i];
#pragma unroll 4
    for (int jj = 0; jj < 64; jj++) {
        const int j = jh * 64 + jj;
        float a0 = b1s[j], a1 = 0.f;
#pragma unroll
        for (int i = 0; i < EDGE_IN; i += 2) {
            a0 += ear[i]     * w1s[i][j];
            a1 += ear[i + 1] * w1s[i + 1][j];
        }
        hl[el][j] = (f16)fmaxf(a0 + a1, 0.f);
    }
    __syncthreads();
    for (int idx = t; idx < 128 * 16; idx += 256) {     // 16 uint4 per 128-f16 row
        const int row = idx >> 4, sg = idx & 15;
        if (e0 + row < N_EDGES) {
            uint4* dp = (uint4*)(out + (size_t)einv[e0 + row] * KDIM) + sg;
            *dp = *((const uint4*)(&hl[row][0]) + sg);
        }
    }
}

// ---------------------------------------------------------------------------
// xf[idx] = f16(x[idx])   (layer 0 input only; later layers get xf from bn_apply)
__global__ __launch_bounds__(256) void xconv(const float* __restrict__ x,
                                             f16* __restrict__ xf, int n) {
    int idx = blockIdx.x * 256 + threadIdx.x;
    if (idx < n) xf[idx] = (f16)x[idx];
}

// ---------------------------------------------------------------------------
// ALL 4 LAYERS in one dispatch (blockIdx.y = layer).
// Bg2[l][C'][i], C' = o*128 + k (k minor) for k<128: w2_l[k][i*64+o];
// rows 8192+o: b2_l[i*64+o] (the per-node bias term ub). f16.
__global__ __launch_bounds__(256) void bconv(const float* __restrict__ e0w2,
                                             const float* __restrict__ e0b2,
                                             const float* __restrict__ ew2,
                                             const float* __restrict__ eb2,
                                             f16* __restrict__ Bg2all) {
    const int l = blockIdx.y;
    const int inshift = l ? 6 : 5;
    const int in = 1 << inshift;
    const float* w2 = (l == 0) ? e0w2 : ew2 + (size_t)(l - 1) * KDIM * HID * HID;
    const float* b2 = (l == 0) ? e0b2 : eb2 + (size_t)(l - 1) * HID * HID;
    f16* Bg2 = Bg2all + (size_t)l * BGSTR;

    const int total = 8256 << inshift;
    int idx = blockIdx.x * 256 + threadIdx.x;
    if (idx >= total) return;
    const int i = idx & (in - 1), C = idx >> inshift;
    float v;
    if (C < 8192) {
        const int k = C & 127, o = C >> 7;
        v = w2[(size_t)k * (in << 6) + (i << 6) + o];
    } else {
        const int o = C - 8192;
        v = b2[(i << 6) + o];
    }
    Bg2[idx] = (f16)v;
}

// ---------------------------------------------------------------------------
// CSR over SRC (constant across layers; built once) + virtual-node list:
// vnode = (node, 16-edge subrange). nv <= NVMAX.
__global__ __launch_bounds__(256) void csr_count(const int* __restrict__ src,
                                                 int* __restrict__ cnt) {
    int e = blockIdx.x * 256 + threadIdx.x;
    if (e < N_EDGES) atomicAdd(&cnt[src[e]], 1);
}

__global__ __launch_bounds__(256) void csr_scan(const int* __restrict__ cnt,
                                                int* __restrict__ row_ptr,
                                                int* __restrict__ cursor,
                                                int* __restrict__ vn_node,
                                                int* __restrict__ vn_rb,
                                                int* __restrict__ nvp) {
    __shared__ int part[256], psum[257];
    __shared__ int vpart[256], vpsum[257];
    const int t = threadIdx.x;
    const int base = t * 40;                       // 256*40 >= 10000
    int s = 0, vs = 0;
    for (int i = 0; i < 40; i++) {
        int idx = base + i;
        if (idx < N_NODES) { int d = cnt[idx]; s += d; vs += (d + 15) >> 4; }
    }
    part[t] = s; vpart[t] = vs;
    __syncthreads();
    if (t == 0) {
        int run = 0, vrun = 0;
        for (int i = 0; i < 256; i++) {
            psum[i] = run;  run += part[i];
            vpsum[i] = vrun; vrun += vpart[i];
        }
        psum[256] = run; vpsum[256] = vrun;
    }
    __syncthreads();
    int run = psum[t], vrun = vpsum[t];
    for (int i = 0; i < 40; i++) {
        int idx = base + i;
        if (idx < N_NODES) {
            int d = cnt[idx];
            row_ptr[idx] = run; cursor[idx] = run;
            int nvn = (d + 15) >> 4;
            for (int j = 0; j < nvn; j++) {
                vn_node[vrun] = idx; vn_rb[vrun] = run + j * 16; vrun++;
            }
            run += d;
        }
    }
    if (t == 255) { row_ptr[N_NODES] = psum[256]; *nvp = vpsum[256]; }
}

__global__ __launch_bounds__(256) void csr_fill(const int* __restrict__ src,
                                                int* __restrict__ cursor,
                                                int* __restrict__ eix,
                                                int* __restrict__ einv) {
    int e = blockIdx.x * 256 + threadIdx.x;
    if (e < N_EDGES) {
        int p = atomicAdd(&cursor[src[e]], 1);
        eix[p] = e;
        einv[e] = p;
    }
}

// ---------------------------------------------------------------------------
// Node-factored NNConv (R10/R11-passing single-buffer indexing + ht prefetch),
// K-SPLIT across gridDim.y=2: segment y owns chunks [y*4, y*4+4). Each segment
// atomically accumulates its partial msg into agg (atomics already required by
// the dst scatter). ub is added by segment 0 only. Grid 782->1564 blocks =>
// LDS-capped 4 blocks/CU stays fed, tail halves.
//   T[n,k,o] = sum_i xf[n,i] * w2[k,i,o]
//   msg[e,o] = sum_k ht[e,k] * T[src,k,o] + ub[src,o];  agg[dst] += msg
__global__ __launch_bounds__(256, 1) void fused_msg2(const f16* __restrict__ htp,
                                                     const f16* __restrict__ xf,
                                                     const f16* __restrict__ Bg2,
                                                     const int* __restrict__ eix,
                                                     const int* __restrict__ row_ptr,
                                                     const int* __restrict__ vn_node,
                                                     const int* __restrict__ vn_rb,
                                                     const int* __restrict__ dst,
                                                     float* __restrict__ agg,
                                                     const int* __restrict__ nvp,
                                                     int inshift) {
    __shared__ f16 tcs[BV * 1024 + 32];   // [slot][(o^(slot&3))][k16] + tail pad
    __shared__ f16 ubs[BV * 68];          // [slot][o] row-padded 64->68
    __shared__ int snd[BV], srb[BV], sct[BV];

    const int t = threadIdx.x;
    const int w = t >> 6, lane = t & 63;
    const int m = lane & 15, q = lane >> 4;
    const int v0 = blockIdx.x * BV;
    const int nv = *nvp;
    if (v0 >= nv) return;
    const bool in64 = (inshift == 6);
    const int cbeg = blockIdx.y * 4, cend = cbeg + 4;   // K-segment (4 chunks)

    for (int i = t; i < BV; i += 256) {
        int v = v0 + i, n = 0, rb = 0, ct = 0;
        if (v < nv) {
            n = vn_node[v]; rb = vn_rb[v];
            int re = row_ptr[n + 1];
            ct = re - rb; if (ct > 16) ct = 16;
        }
        snd[i] = n; srb[i] = rb; sct[i] = ct;
    }
    // zero the tail pad (vn=BV-1, q>=2 lanes read it with zero-A; stale NaN
    // would poison 0*x)
    if (t < 8) *(uint2*)(tcs + BV * 1024 + t * 4) = (uint2){0u, 0u};
    __syncthreads();

    // T-phase B-fragment: xf row of slot m (N dim = the 16 slots)
    v8h bfx[2];
    {
        const size_t nb = (size_t)snd[m] << inshift;
        bfx[0] = *(const v8h*)(xf + nb + q * 8);
        if (in64) bfx[1] = *(const v8h*)(xf + nb + 32 + q * 8);
    }

    // chunk-invariant htp row pointer per j (this lane's edge slot of vnode)
    const f16* hrow[4];
#pragma unroll
    for (int j = 0; j < 4; j++) {
        const int vn = (w << 2) + j;
        const int rb = srb[vn], ct = sct[vn];
        const int es = (m < ct) ? m : (ct > 0 ? ct - 1 : 0);
        hrow[j] = htp + (size_t)(rb + es) * KDIM;
    }

    v4f acc[4][4];
#pragma unroll
    for (int j = 0; j < 4; j++)
#pragma unroll
        for (int ot = 0; ot < 4; ot++) acc[j][ot] = (v4f){0.f, 0.f, 0.f, 0.f};

    for (int c = cbeg; c < cend; c++) {
        // ---- prefetch this chunk's app-phase ht fragments (latency hides
        // under the T-phase; drained by the pre-app barrier)
        v8h hpre[4];
#pragma unroll
        for (int j = 0; j < 4; j++) {
            v8h tmp;
#pragma unroll
            for (int z = 0; z < 8; z++) tmp[z] = (f16)0.f;
            if (q < 2)      // lanes q>=2 are k 16..31 of the MFMA: zero (K=16 pad)
                tmp = *(const v8h*)(hrow[j] + (c << 4) + q * 8);
            hpre[j] = tmp;
        }
        // ---- T-phase: wave w computes o in [w*16, w*16+16), all 16 slots.
        // D (16x16): row = q*4+reg -> k within chunk, col = m -> slot.
#pragma unroll 4
        for (int ol = 0; ol < 16; ol++) {
            const int o = (w << 4) + ol;
            const size_t arow = ((size_t)(o * 128 + (c << 4) + m)) << inshift;
            v8h a0 = *(const v8h*)(Bg2 + arow + q * 8);
            v8h a1;
            if (in64) a1 = *(const v8h*)(Bg2 + arow + 32 + q * 8);
            v4f d = (v4f){0.f, 0.f, 0.f, 0.f};
            d = __builtin_amdgcn_mfma_f32_16x16x32_f16(a0, bfx[0], d, 0, 0, 0);
            if (in64)
                d = __builtin_amdgcn_mfma_f32_16x16x32_f16(a1, bfx[1], d, 0, 0, 0);
            const int sl = m;                         // SLOT index
            union { f16 x[4]; uint2 u; } pk;
            pk.x[0] = (f16)d[0]; pk.x[1] = (f16)d[1];
            pk.x[2] = (f16)d[2]; pk.x[3] = (f16)d[3];
            *(uint2*)(tcs + sl * 1024 + ((o ^ (sl & 3)) << 4) + (q << 2)) = pk.u;
        }
        __syncthreads();
        // ---- app-phase: wave w applies vnode slots w*4 .. w*4+3
#pragma unroll
        for (int j = 0; j < 4; j++) {
            const int vn = (w << 2) + j;              // SLOT index 0..15
            const f16* tb = tcs + vn * 1024;
            const int nx = vn & 3;
#pragma unroll
            for (int ot = 0; ot < 4; ot++) {
                v8h hb = *(const v8h*)(tb + ((((ot << 4) + m) ^ nx) << 4) + (q << 3));
                acc[j][ot] = __builtin_amdgcn_mfma_f32_16x16x32_f16(hpre[j], hb,
                                                                    acc[j][ot], 0, 0, 0);
            }
        }
        __syncthreads();
    }

    // ---- ub mini-chunk (segment 0 only): ub[slot][o] = sum_i xf[n,i] b2[i,o]
    if (blockIdx.y == 0) {
        const size_t arow = ((size_t)(8192 + (w << 4) + m)) << inshift;
        v8h a0 = *(const v8h*)(Bg2 + arow + q * 8);
        v4f d = (v4f){0.f, 0.f, 0.f, 0.f};
        d = __builtin_amdgcn_mfma_f32_16x16x32_f16(a0, bfx[0], d, 0, 0, 0);
        if (in64) {
            v8h a1 = *(const v8h*)(Bg2 + arow + 32 + q * 8);
            d = __builtin_amdgcn_mfma_f32_16x16x32_f16(a1, bfx[1], d, 0, 0, 0);
        }
        const int sl = m;                             // SLOT index
        union { f16 x[4]; uint2 u; } pk;
        pk.x[0] = (f16)d[0]; pk.x[1] = (f16)d[1];
        pk.x[2] = (f16)d[2]; pk.x[3] = (f16)d[3];
        *(uint2*)(ubs + sl * 68 + (w << 4) + (q << 2)) = pk.u;
    }
    __syncthreads();

    // ---- epilogue: scatter acc (+ ub for segment 0) into agg by dst
#pragma unroll
    for (int j = 0; j < 4; j++) {
        const int vn = (w << 2) + j;                  // SLOT index
        const int rb = srb[vn], ct = sct[vn];
        if (ct == 0) continue;                        // wave-uniform
        int dr[4];
#pragma unroll
        for (int r = 0; r < 4; r++) {
            const int es = (q << 2) + r;
            dr[r] = (es < ct) ? dst[eix[rb + es]] : -1;
        }
#pragma unroll
        for (int ot = 0; ot < 4; ot++) {
            float ub = 0.f;
            if (blockIdx.y == 0) ub = (float)ubs[vn * 68 + (ot << 4) + m];
#pragma unroll
            for (int r = 0; r < 4; r++)
                if (dr[r] >= 0)
                    atomicAdd(&agg[(size_t)dr[r] * 64 + (ot << 4) + m],
                              acc[j][ot][r] + ub);
        }
    }
}

// ---------------------------------------------------------------------------
// pre[n,o] = agg[n,o] + sum_i x[n,i]*root[i,o] + bias[o]; accumulate BN stats.
__global__ __launch_bounds__(256) void pre_stats(const float* __restrict__ agg,
                                                 const float* __restrict__ x,
                                                 const float* __restrict__ root,
                                                 const float* __restrict__ bias,
                                                 float* __restrict__ pre,
                                                 float* __restrict__ stats,
                                                 int in, int inshift) {
    __shared__ float xs[4][64];
    __shared__ float lsum[64], lsq[64];
    const int o = threadIdx.x & 63, nl = threadIdx.x >> 6;
    if (threadIdx.x < 64) { lsum[threadIdx.x] = 0.f; lsq[threadIdx.x] = 0.f; }
    const float bo = bias[o];
    for (int n0 = blockIdx.x * 4; n0 < N_NODES; n0 += gridDim.x * 4) {
        __syncthreads();
        for (int idx = threadIdx.x; idx < (4 << inshift); idx += 256) {
            int r = idx >> inshift, i = idx & (in - 1);
            if (n0 + r < N_NODES) xs[r][i] = x[(size_t)(n0 + r) * in + i];
        }
        __syncthreads();
        int n = n0 + nl;
        if (n < N_NODES) {
            float acc = agg[(size_t)n * 64 + o] + bo;
#pragma unroll 8
            for (int i = 0; i < in; i++) acc += xs[nl][i] * root[i * 64 + o];
            pre[(size_t)n * 64 + o] = acc;
            atomicAdd(&lsum[o], acc);
            atomicAdd(&lsq[o], acc * acc);
        }
    }
    __syncthreads();
    if (threadIdx.x < 64) {
        atomicAdd(&stats[threadIdx.x], lsum[threadIdx.x]);
        atomicAdd(&stats[64 + threadIdx.x], lsq[threadIdx.x]);
    }
}

// ---------------------------------------------------------------------------
// BN (batch stats, biased var) + ReLU. Zeroes pre(=agg) after its single read
// (replaces the per-layer agg memset). mode 0: store xn (f32) + xf (f16, input
// to next layer's fused T-phase). mode 1: segment-max pool.
__global__ __launch_bounds__(256) void bn_apply(float* __restrict__ pre,
                                                const float* __restrict__ stats,
                                                const float* __restrict__ gamma,
                                                const float* __restrict__ beta,
                                                float* __restrict__ xn,
                                                f16* __restrict__ xfo,
                                                const int* __restrict__ batch,
                                                float* __restrict__ pooled,
                                                int mode) {
    int idx = blockIdx.x * 256 + threadIdx.x;
    if (idx >= N_NODES * 64) return;
    const int o = idx & 63, n = idx >> 6;
    const float inv = 1.f / (float)N_NODES;
    float mu = stats[o] * inv;
    float var = stats[64 + o] * inv - mu * mu;
    float sc = gamma[o] * rsqrtf(var + EPS);
    float sh = beta[o] - mu * sc;
    float p = pre[idx];
    pre[idx] = 0.f;                     // agg zeroed for the next layer's fused
    float v = fmaxf(p * sc + sh, 0.f);
    if (mode == 0) { xn[idx] = v; xfo[idx] = (f16)v; }
    else atomicMax((int*)&pooled[(size_t)batch[n] * 64 + o], __float_as_int(v));
}

// ---------------------------------------------------------------------------
// out[g] = pp_b2 + relu(cat(pooled[g],u[g]) @ pp_w1 + pp_b1) @ pp_w2
__global__ __launch_bounds__(64) void final_mlp(const float* __restrict__ pooled,
                                                const float* __restrict__ u,
                                                const float* __restrict__ w1,
                                                const float* __restrict__ b1,
                                                const float* __restrict__ w2,
                                                const float* __restrict__ b2,
                                                float* __restrict__ out) {
    const int g = blockIdx.x, t = threadIdx.x;
    float acc = b1[t];
#pragma unroll 8
    for (int i = 0; i < 64; i++) acc += pooled[g * 64 + i] * w1[i * 64 + t];
#pragma unroll
    for (int j = 0; j < GIN; j++) acc += u[g * GIN + j] * w1[(64 + j) * 64 + t];
    float hv = fmaxf(acc, 0.f) * w2[t];
#pragma unroll
    for (int off = 32; off > 0; off >>= 1) hv += __shfl_down(hv, off, 64);
    if (t == 0) out[g] = hv + b2[0];
}

// ---------------------------------------------------------------------------
extern "C" void kernel_launch(void* const* d_in, const int* in_sizes, int n_in,
                              void* d_out, int out_size, void* d_ws, size_t ws_size,
                              hipStream_t stream) {
    const float* x0      = (const float*)d_in[0];
    const int*   ei      = (const int*)d_in[1];
    const int*   src     = ei;
    const int*   dst     = ei + N_EDGES;
    const float* ea      = (const float*)d_in[2];
    const int*   batch   = (const int*)d_in[3];
    const float* u       = (const float*)d_in[4];
    const float* e0w1    = (const float*)d_in[5];
    const float* e0b1    = (const float*)d_in[6];
    const float* e0w2    = (const float*)d_in[7];
    const float* e0b2    = (const float*)d_in[8];
    const float* root0   = (const float*)d_in[9];
    const float* bias0   = (const float*)d_in[10];
    const float* gamma0  = (const float*)d_in[11];
    const float* beta0   = (const float*)d_in[12];
    const float* ew1     = (const float*)d_in[13];
    const float* eb1     = (const float*)d_in[14];
    const float* ew2     = (const float*)d_in[15];
    const float* eb2     = (const float*)d_in[16];
    const float* rootl   = (const float*)d_in[17];
    const float* biasl   = (const float*)d_in[18];
    const float* gammal  = (const float*)d_in[19];
    const float* betal   = (const float*)d_in[20];
    const float* pp_w1   = (const float*)d_in[21];
    const float* pp_b1   = (const float*)d_in[22];
    const float* pp_w2   = (const float*)d_in[23];
    const float* pp_b2   = (const float*)d_in[24];

    float* ws = (float*)d_ws;
    size_t off = 0;
    f16*   htp    = (f16*)(ws + off); off += 4 * HTSTR / 2;        // 51.2 MB
    f16*   xf     = (f16*)(ws + off); off += (size_t)N_NODES * 64 / 2;
    f16*   Bg2    = (f16*)(ws + off); off += 4 * BGSTR / 2;        // 4.2 MB
    float* agg    = ws + off; off += (size_t)N_NODES * 64;
    float* xa     = ws + off; off += (size_t)N_NODES * 64;
    float* xb     = ws + off; off += (size_t)N_NODES * 64;
    float* stats  = ws + off; off += 4 * 128 + 64;
    float* pooled = ws + off; off += (size_t)NG * 64;
    int*   row_ptr = (int*)(ws + off); off += 10008;
    int*   cursor  = (int*)(ws + off); off += 10000;
    int*   cnt     = (int*)(ws + off); off += 10000;
    int*   eix     = (int*)(ws + off); off += N_EDGES;
    int*   einv    = (int*)(ws + off); off += N_EDGES;
    int*   vn_node = (int*)(ws + off); off += NVMAX + 12;
    int*   vn_rb   = (int*)(ws + off); off += NVMAX + 12;
    int*   nvp     = (int*)(ws + off); off += 8;

    const int eblocks = (N_EDGES + 255) / 256;               // 196
    const int hblocks = (N_EDGES + 127) / 128;               // 391
    const int bblocks = ((8256 << 6) + 255) / 256;           // 2064
    const int fblocks = (NVMAX + BV - 1) / BV;               // 782
    const int ablocks = (N_NODES * 64 + 255) / 256;

    // ---- head: layer-independent work, once
    hipMemsetAsync(pooled, 0, (size_t)NG * 64 * 4, stream);
    hipMemsetAsync(agg, 0, (size_t)N_NODES * 64 * 4, stream);
    hipMemsetAsync(stats, 0, 4 * 128 * 4, stream);
    hipMemsetAsync(cnt, 0, N_NODES * 4, stream);
    csr_count<<<eblocks, 256, 0, stream>>>(src, cnt);
    csr_scan<<<1, 256, 0, stream>>>(cnt, row_ptr, cursor, vn_node, vn_rb, nvp);
    csr_fill<<<eblocks, 256, 0, stream>>>(src, cursor, eix, einv);
    ht_kernel<<<dim3(hblocks, 4), 256, 0, stream>>>(ea, e0w1, e0b1, ew1, eb1,
                                                    einv, htp);
    bconv<<<dim3(bblocks, 4), 256, 0, stream>>>(e0w2, e0b2, ew2, eb2, Bg2);
    xconv<<<(N_NODES * IN0 + 255) / 256, 256, 0, stream>>>(x0, xf, N_NODES * IN0);

    struct Layer {
        const float *root, *bias, *gamma, *beta, *xin;
        float* xout; int in, inshift, mode;
    };
    Layer L[4];
    L[0] = {root0, bias0, gamma0, beta0, x0, xa, IN0, 5, 0};
    for (int l = 0; l < 3; l++) {
        const float* xin  = (l == 0) ? xa : ((l == 1) ? xb : xa);
        float*       xout = (l == 0) ? xb : ((l == 1) ? xa : nullptr);
        L[l + 1] = {rootl + (size_t)l * HID * HID, biasl + (size_t)l * HID,
                    gammal + (size_t)l * HID, betal + (size_t)l * HID,
                    xin, xout, HID, 6, (l == 2) ? 1 : 0};
    }

    // ---- per-layer critical path: fused -> pre_stats -> bn_apply
    for (int l = 0; l < 4; l++) {
        const Layer& P = L[l];
        fused_msg2<<<dim3(fblocks, 2), 256, 0, stream>>>(htp + (size_t)l * HTSTR, xf,
                                                         Bg2 + (size_t)l * BGSTR, eix,
                                                         row_ptr, vn_node, vn_rb, dst,
                                                         agg, nvp, P.inshift);
        pre_stats<<<512, 256, 0, stream>>>(agg, P.xin, P.root, P.bias, agg,
                                           stats + l * 128, P.in, P.inshift);
        bn_apply<<<ablocks, 256, 0, stream>>>(agg, stats + l * 128, P.gamma,
                                              P.beta, P.xout, xf, batch, pooled,
                                              P.mode);
    }
    final_mlp<<<NG, 64, 0, stream>>>(pooled, u, pp_w1, pp_b1, pp_w2, pp_b2,
                                     (float*)d_out);
}

// Round 14
// 743.893 us; speedup vs baseline: 1.1487x; 1.0040x over previous
//
#include <hip/hip_runtime.h>

#define N_NODES 10000
#define N_EDGES 50000
#define IN0     32
#define EDGE_IN 16
#define GIN     8
#define HID     64
#define NG      64
#define KDIM    128
#define BV      16        // virtual nodes per fused block
#define NVMAX   12500     // sum ceil(deg/16) <= (E + 15*N)/16
#define EPS     1e-5f

typedef _Float16 f16;
typedef _Float16 v8h __attribute__((ext_vector_type(8)));
typedef float    v4f __attribute__((ext_vector_type(4)));

#define HTSTR ((size_t)N_EDGES * KDIM)      // per-layer htp stride (f16)
#define BGSTR ((size_t)8256 * 64)           // per-layer Bg2 stride (f16)

// ---------------------------------------------------------------------------
// ALL 4 LAYERS in one dispatch (blockIdx.y = layer). htp[l][einv[e]][j] =
// f16(relu(ea[e]@w1_l[:,j] + b1_l[j])), rows permuted into src-CSR order.
// Hot loop reads: ea from REGISTERS, w1/b1 from LDS (wave-uniform broadcast).
__global__ __launch_bounds__(256) void ht_kernel(const float* __restrict__ ea,
                                                 const float* __restrict__ e0w1,
                                                 const float* __restrict__ e0b1,
                                                 const float* __restrict__ ew1,
                                                 const float* __restrict__ eb1,
                                                 const int* __restrict__ einv,
                                                 f16* __restrict__ htp) {
    const int l = blockIdx.y;
    const float* w1 = (l == 0) ? e0w1 : ew1 + (size_t)(l - 1) * EDGE_IN * KDIM;
    const float* b1 = (l == 0) ? e0b1 : eb1 + (size_t)(l - 1) * KDIM;
    f16* out = htp + (size_t)l * HTSTR;

    __shared__ float w1s[EDGE_IN][KDIM + 1];   // 8.3 KB
    __shared__ float b1s[KDIM];                // 0.5 KB
    __shared__ float eas[128][17];             // 8.7 KB
    __shared__ f16 hl[128][136];               // 34.8 KB
    const int e0 = blockIdx.x * 128, t = threadIdx.x;
    for (int idx = t; idx < EDGE_IN * KDIM; idx += 256)
        w1s[idx >> 7][idx & 127] = w1[idx];
    if (t < KDIM) b1s[t] = b1[t];
    for (int idx = t; idx < 128 * 16; idx += 256) {
        int r = idx >> 4, i = idx & 15;
        eas[r][i] = (e0 + r < N_EDGES) ? ea[(size_t)(e0 + r) * EDGE_IN + i] : 0.f;
    }
    __syncthreads();
    const int el = t & 127, jh = t >> 7;
    float ear[EDGE_IN];
#pragma unroll
    for (int i = 0; i < EDGE_IN; i++) ear[i] = eas[el][i];
#pragma unroll 4
    for (int jj = 0; jj < 64; jj++) {
        const int j = jh * 64 + jj;
        float a0 = b1s[j], a1 = 0.f;
#pragma unroll
        for (int i = 0; i < EDGE_IN; i += 2) {
            a0 += ear[i]     * w1s[i][j];
            a1 += ear[i + 1] * w1s[i + 1][j];
        }
        hl[el][j] = (f16)fmaxf(a0 + a1, 0.f);
    }
    __syncthreads();
    for (int idx = t; idx < 128 * 16; idx += 256) {     // 16 uint4 per 128-f16 row
        const int row = idx >> 4, sg = idx & 15;
        if (e0 + row < N_EDGES) {
            uint4* dp = (uint4*)(out + (size_t)einv[e0 + row] * KDIM) + sg;
            *dp = *((const uint4*)(&hl[row][0]) + sg);
        }
    }
}

// ---------------------------------------------------------------------------
// xf[idx] = f16(x[idx])   (layer 0 input only; later layers get xf from bn_apply)
__global__ __launch_bounds__(256) void xconv(const float* __restrict__ x,
                                             f16* __restrict__ xf, int n) {
    int idx = blockIdx.x * 256 + threadIdx.x;
    if (idx < n) xf[idx] = (f16)x[idx];
}

// ---------------------------------------------------------------------------
// ALL 4 LAYERS in one dispatch (blockIdx.y = layer).
// Bg2[l][C'][i], C' = o*128 + k (k minor) for k<128: w2_l[k][i*64+o];
// rows 8192+o: b2_l[i*64+o] (the per-node bias term ub). f16.
__global__ __launch_bounds__(256) void bconv(const float* __restrict__ e0w2,
                                             const float* __restrict__ e0b2,
                                             const float* __restrict__ ew2,
                                             const float* __restrict__ eb2,
                                             f16* __restrict__ Bg2all) {
    const int l = blockIdx.y;
    const int inshift = l ? 6 : 5;
    const int in = 1 << inshift;
    const float* w2 = (l == 0) ? e0w2 : ew2 + (size_t)(l - 1) * KDIM * HID * HID;
    const float* b2 = (l == 0) ? e0b2 : eb2 + (size_t)(l - 1) * HID * HID;
    f16* Bg2 = Bg2all + (size_t)l * BGSTR;

    const int total = 8256 << inshift;
    int idx = blockIdx.x * 256 + threadIdx.x;
    if (idx >= total) return;
    const int i = idx & (in - 1), C = idx >> inshift;
    float v;
    if (C < 8192) {
        const int k = C & 127, o = C >> 7;
        v = w2[(size_t)k * (in << 6) + (i << 6) + o];
    } else {
        const int o = C - 8192;
        v = b2[(i << 6) + o];
    }
    Bg2[idx] = (f16)v;
}

// ---------------------------------------------------------------------------
// CSR over SRC (constant across layers; built once) + virtual-node list:
// vnode = (node, 16-edge subrange). nv <= NVMAX.
__global__ __launch_bounds__(256) void csr_count(const int* __restrict__ src,
                                                 int* __restrict__ cnt) {
    int e = blockIdx.x * 256 + threadIdx.x;
    if (e < N_EDGES) atomicAdd(&cnt[src[e]], 1);
}

__global__ __launch_bounds__(256) void csr_scan(const int* __restrict__ cnt,
                                                int* __restrict__ row_ptr,
                                                int* __restrict__ cursor,
                                                int* __restrict__ vn_node,
                                                int* __restrict__ vn_rb,
                                                int* __restrict__ nvp) {
    __shared__ int part[256], psum[257];
    __shared__ int vpart[256], vpsum[257];
    const int t = threadIdx.x;
    const int base = t * 40;                       // 256*40 >= 10000
    int s = 0, vs = 0;
    for (int i = 0; i < 40; i++) {
        int idx = base + i;
        if (idx < N_NODES) { int d = cnt[idx]; s += d; vs += (d + 15) >> 4; }
    }
    part[t] = s; vpart[t] = vs;
    __syncthreads();
    if (t == 0) {
        int run = 0, vrun = 0;
        for (int i = 0; i < 256; i++) {
            psum[i] = run;  run += part[i];
            vpsum[i] = vrun; vrun += vpart[i];
        }
        psum[256] = run; vpsum[256] = vrun;
    }
    __syncthreads();
    int run = psum[t], vrun = vpsum[t];
    for (int i = 0; i < 40; i++) {
        int idx = base + i;
        if (idx < N_NODES) {
            int d = cnt[idx];
            row_ptr[idx] = run; cursor[idx] = run;
            int nvn = (d + 15) >> 4;
            for (int j = 0; j < nvn; j++) {
                vn_node[vrun] = idx; vn_rb[vrun] = run + j * 16; vrun++;
            }
            run += d;
        }
    }
    if (t == 255) { row_ptr[N_NODES] = psum[256]; *nvp = vpsum[256]; }
}

__global__ __launch_bounds__(256) void csr_fill(const int* __restrict__ src,
                                                int* __restrict__ cursor,
                                                int* __restrict__ eix,
                                                int* __restrict__ einv) {
    int e = blockIdx.x * 256 + threadIdx.x;
    if (e < N_EDGES) {
        int p = atomicAdd(&cursor[src[e]], 1);
        eix[p] = e;
        einv[e] = p;
    }
}

// ---------------------------------------------------------------------------
// Node-factored NNConv. Same indexing as the R10/R13-passing kernel, but
// 512 THREADS (8 waves) per block at the same 35KB LDS: per-wave work halves
// (T-phase: 8 o's/wave; app: 2 vnodes/wave; ub: waves 0-3) while waves/CU
// triples (~8 -> ~24) -- the T-phase L2-load latency chain (R13 diagnosis:
// ~100cy/iter retired, every throughput counter idle) gets 3x the hiding.
// K-split across gridDim.y=2 (chunks [y*4, y*4+4)) kept for grid fill.
//   T[n,k,o] = sum_i xf[n,i] * w2[k,i,o]
//   msg[e,o] = sum_k ht[e,k] * T[src,k,o] + ub[src,o];  agg[dst] += msg
__global__ __launch_bounds__(512) void fused_msg2(const f16* __restrict__ htp,
                                                  const f16* __restrict__ xf,
                                                  const f16* __restrict__ Bg2,
                                                  const int* __restrict__ eix,
                                                  const int* __restrict__ row_ptr,
                                                  const int* __restrict__ vn_node,
                                                  const int* __restrict__ vn_rb,
                                                  const int* __restrict__ dst,
                                                  float* __restrict__ agg,
                                                  const int* __restrict__ nvp,
                                                  int inshift) {
    __shared__ f16 tcs[BV * 1024 + 32];   // [slot][(o^(slot&3))][k16] + tail pad
    __shared__ f16 ubs[BV * 68];          // [slot][o] row-padded 64->68
    __shared__ int snd[BV], srb[BV], sct[BV];

    const int t = threadIdx.x;
    const int w = t >> 6, lane = t & 63;  // w = 0..7
    const int m = lane & 15, q = lane >> 4;
    const int v0 = blockIdx.x * BV;
    const int nv = *nvp;
    if (v0 >= nv) return;
    const bool in64 = (inshift == 6);
    const int cbeg = blockIdx.y * 4, cend = cbeg + 4;   // K-segment (4 chunks)

    if (t < BV) {
        int v = v0 + t, n = 0, rb = 0, ct = 0;
        if (v < nv) {
            n = vn_node[v]; rb = vn_rb[v];
            int re = row_ptr[n + 1];
            ct = re - rb; if (ct > 16) ct = 16;
        }
        snd[t] = n; srb[t] = rb; sct[t] = ct;
    }
    // zero the tail pad (vn=BV-1, q>=2 lanes read it with zero-A; stale NaN
    // would poison 0*x)
    if (t >= 32 && t < 40) *(uint2*)(tcs + BV * 1024 + (t - 32) * 4) = (uint2){0u, 0u};
    __syncthreads();

    // T-phase B-fragment: xf row of slot m (N dim = the 16 slots)
    v8h bfx[2];
    {
        const size_t nb = (size_t)snd[m] << inshift;
        bfx[0] = *(const v8h*)(xf + nb + q * 8);
        if (in64) bfx[1] = *(const v8h*)(xf + nb + 32 + q * 8);
    }

    // chunk-invariant htp row pointer per j (this lane's edge slot of vnode)
    const f16* hrow[2];
#pragma unroll
    for (int j = 0; j < 2; j++) {
        const int vn = (w << 1) + j;
        const int rb = srb[vn], ct = sct[vn];
        const int es = (m < ct) ? m : (ct > 0 ? ct - 1 : 0);
        hrow[j] = htp + (size_t)(rb + es) * KDIM;
    }

    v4f acc[2][4];
#pragma unroll
    for (int j = 0; j < 2; j++)
#pragma unroll
        for (int ot = 0; ot < 4; ot++) acc[j][ot] = (v4f){0.f, 0.f, 0.f, 0.f};

    for (int c = cbeg; c < cend; c++) {
        // ---- prefetch this chunk's app-phase ht fragments (latency hides
        // under the T-phase; drained by the pre-app barrier)
        v8h hpre[2];
#pragma unroll
        for (int j = 0; j < 2; j++) {
            v8h tmp;
#pragma unroll
            for (int z = 0; z < 8; z++) tmp[z] = (f16)0.f;
            if (q < 2)      // lanes q>=2 are k 16..31 of the MFMA: zero (K=16 pad)
                tmp = *(const v8h*)(hrow[j] + (c << 4) + q * 8);
            hpre[j] = tmp;
        }
        // ---- T-phase: wave w computes o in [w*8, w*8+8), all 16 slots.
        // D (16x16): row = q*4+reg -> k within chunk, col = m -> slot.
#pragma unroll 4
        for (int ol = 0; ol < 8; ol++) {
            const int o = (w << 3) + ol;
            const size_t arow = ((size_t)(o * 128 + (c << 4) + m)) << inshift;
            v8h a0 = *(const v8h*)(Bg2 + arow + q * 8);
            v8h a1;
            if (in64) a1 = *(const v8h*)(Bg2 + arow + 32 + q * 8);
            v4f d = (v4f){0.f, 0.f, 0.f, 0.f};
            d = __builtin_amdgcn_mfma_f32_16x16x32_f16(a0, bfx[0], d, 0, 0, 0);
            if (in64)
                d = __builtin_amdgcn_mfma_f32_16x16x32_f16(a1, bfx[1], d, 0, 0, 0);
            const int sl = m;                         // SLOT index
            union { f16 x[4]; uint2 u; } pk;
            pk.x[0] = (f16)d[0]; pk.x[1] = (f16)d[1];
            pk.x[2] = (f16)d[2]; pk.x[3] = (f16)d[3];
            *(uint2*)(tcs + sl * 1024 + ((o ^ (sl & 3)) << 4) + (q << 2)) = pk.u;
        }
        __syncthreads();
        // ---- app-phase: wave w applies vnode slots w*2 .. w*2+1
#pragma unroll
        for (int j = 0; j < 2; j++) {
            const int vn = (w << 1) + j;              // SLOT index 0..15
            const f16* tb = tcs + vn * 1024;
            const int nx = vn & 3;
#pragma unroll
            for (int ot = 0; ot < 4; ot++) {
                v8h hb = *(const v8h*)(tb + ((((ot << 4) + m) ^ nx) << 4) + (q << 3));
                acc[j][ot] = __builtin_amdgcn_mfma_f32_16x16x32_f16(hpre[j], hb,
                                                                    acc[j][ot], 0, 0, 0);
            }
        }
        __syncthreads();
    }

    // ---- ub mini-chunk (segment 0, waves 0-3): ub[slot][o] = xf[n,:]@b2[:,o]
    if (blockIdx.y == 0 && w < 4) {
        const size_t arow = ((size_t)(8192 + (w << 4) + m)) << inshift;
        v8h a0 = *(const v8h*)(Bg2 + arow + q * 8);
        v4f d = (v4f){0.f, 0.f, 0.f, 0.f};
        d = __builtin_amdgcn_mfma_f32_16x16x32_f16(a0, bfx[0], d, 0, 0, 0);
        if (in64) {
            v8h a1 = *(const v8h*)(Bg2 + arow + 32 + q * 8);
            d = __builtin_amdgcn_mfma_f32_16x16x32_f16(a1, bfx[1], d, 0, 0, 0);
        }
        const int sl = m;                             // SLOT index
        union { f16 x[4]; uint2 u; } pk;
        pk.x[0] = (f16)d[0]; pk.x[1] = (f16)d[1];
        pk.x[2] = (f16)d[2]; pk.x[3] = (f16)d[3];
        *(uint2*)(ubs + sl * 68 + (w << 4) + (q << 2)) = pk.u;
    }
    __syncthreads();

    // ---- epilogue: scatter acc (+ ub for segment 0) into agg by dst
#pragma unroll
    for (int j = 0; j < 2; j++) {
        const int vn = (w << 1) + j;                  // SLOT index
        const int rb = srb[vn], ct = sct[vn];
        if (ct == 0) continue;                        // wave-uniform
        int dr[4];
#pragma unroll
        for (int r = 0; r < 4; r++) {
            const int es = (q << 2) + r;
            dr[r] = (es < ct) ? dst[eix[rb + es]] : -1;
        }
#pragma unroll
        for (int ot = 0; ot < 4; ot++) {
            float ub = 0.f;
            if (blockIdx.y == 0) ub = (float)ubs[vn * 68 + (ot << 4) + m];
#pragma unroll
            for (int r = 0; r < 4; r++)
                if (dr[r] >= 0)
                    atomicAdd(&agg[(size_t)dr[r] * 64 + (ot << 4) + m],
                              acc[j][ot][r] + ub);
        }
    }
}

// ---------------------------------------------------------------------------
// pre[n,o] = agg[n,o] + sum_i x[n,i]*root[i,o] + bias[o]; accumulate BN stats.
__global__ __launch_bounds__(256) void pre_stats(const float* __restrict__ agg,
                                                 const float* __restrict__ x,
                                                 const float* __restrict__ root,
                                                 const float* __restrict__ bias,
                                                 float* __restrict__ pre,
                                                 float* __restrict__ stats,
                                                 int in, int inshift) {
    __shared__ float xs[4][64];
    __shared__ float lsum[64], lsq[64];
    const int o = threadIdx.x & 63, nl = threadIdx.x >> 6;
    if (threadIdx.x < 64) { lsum[threadIdx.x] = 0.f; lsq[threadIdx.x] = 0.f; }
    const float bo = bias[o];
    for (int n0 = blockIdx.x * 4; n0 < N_NODES; n0 += gridDim.x * 4) {
        __syncthreads();
        for (int idx = threadIdx.x; idx < (4 << inshift); idx += 256) {
            int r = idx >> inshift, i = idx & (in - 1);
            if (n0 + r < N_NODES) xs[r][i] = x[(size_t)(n0 + r) * in + i];
        }
        __syncthreads();
        int n = n0 + nl;
        if (n < N_NODES) {
            float acc = agg[(size_t)n * 64 + o] + bo;
#pragma unroll 8
            for (int i = 0; i < in; i++) acc += xs[nl][i] * root[i * 64 + o];
            pre[(size_t)n * 64 + o] = acc;
            atomicAdd(&lsum[o], acc);
            atomicAdd(&lsq[o], acc * acc);
        }
    }
    __syncthreads();
    if (threadIdx.x < 64) {
        atomicAdd(&stats[threadIdx.x], lsum[threadIdx.x]);
        atomicAdd(&stats[64 + threadIdx.x], lsq[threadIdx.x]);
    }
}

// ---------------------------------------------------------------------------
// BN (batch stats, biased var) + ReLU. Zeroes pre(=agg) after its single read
// (replaces the per-layer agg memset). mode 0: store xn (f32) + xf (f16, input
// to next layer's fused T-phase). mode 1: segment-max pool.
__global__ __launch_bounds__(256) void bn_apply(float* __restrict__ pre,
                                                const float* __restrict__ stats,
                                                const float* __restrict__ gamma,
                                                const float* __restrict__ beta,
                                                float* __restrict__ xn,
                                                f16* __restrict__ xfo,
                                                const int* __restrict__ batch,
                                                float* __restrict__ pooled,
                                                int mode) {
    int idx = blockIdx.x * 256 + threadIdx.x;
    if (idx >= N_NODES * 64) return;
    const int o = idx & 63, n = idx >> 6;
    const float inv = 1.f / (float)N_NODES;
    float mu = stats[o] * inv;
    float var = stats[64 + o] * inv - mu * mu;
    float sc = gamma[o] * rsqrtf(var + EPS);
    float sh = beta[o] - mu * sc;
    float p = pre[idx];
    pre[idx] = 0.f;                     // agg zeroed for the next layer's fused
    float v = fmaxf(p * sc + sh, 0.f);
    if (mode == 0) { xn[idx] = v; xfo[idx] = (f16)v; }
    else atomicMax((int*)&pooled[(size_t)batch[n] * 64 + o], __float_as_int(v));
}

// ---------------------------------------------------------------------------
// out[g] = pp_b2 + relu(cat(pooled[g],u[g]) @ pp_w1 + pp_b1) @ pp_w2
__global__ __launch_bounds__(64) void final_mlp(const float* __restrict__ pooled,
                                                const float* __restrict__ u,
                                                const float* __restrict__ w1,
                                                const float* __restrict__ b1,
                                                const float* __restrict__ w2,
                                                const float* __restrict__ b2,
                                                float* __restrict__ out) {
    const int g = blockIdx.x, t = threadIdx.x;
    float acc = b1[t];
#pragma unroll 8
    for (int i = 0; i < 64; i++) acc += pooled[g * 64 + i] * w1[i * 64 + t];
#pragma unroll
    for (int j = 0; j < GIN; j++) acc += u[g * GIN + j] * w1[(64 + j) * 64 + t];
    float hv = fmaxf(acc, 0.f) * w2[t];
#pragma unroll
    for (int off = 32; off > 0; off >>= 1) hv += __shfl_down(hv, off, 64);
    if (t == 0) out[g] = hv + b2[0];
}

// ---------------------------------------------------------------------------
extern "C" void kernel_launch(void* const* d_in, const int* in_sizes, int n_in,
                              void* d_out, int out_size, void* d_ws, size_t ws_size,
                              hipStream_t stream) {
    const float* x0      = (const float*)d_in[0];
    const int*   ei      = (const int*)d_in[1];
    const int*   src     = ei;
    const int*   dst     = ei + N_EDGES;
    const float* ea      = (const float*)d_in[2];
    const int*   batch   = (const int*)d_in[3];
    const float* u       = (const float*)d_in[4];
    const float* e0w1    = (const float*)d_in[5];
    const float* e0b1    = (const float*)d_in[6];
    const float* e0w2    = (const float*)d_in[7];
    const float* e0b2    = (const float*)d_in[8];
    const float* root0   = (const float*)d_in[9];
    const float* bias0   = (const float*)d_in[10];
    const float* gamma0  = (const float*)d_in[11];
    const float* beta0   = (const float*)d_in[12];
    const float* ew1     = (const float*)d_in[13];
    const float* eb1     = (const float*)d_in[14];
    const float* ew2     = (const float*)d_in[15];
    const float* eb2     = (const float*)d_in[16];
    const float* rootl   = (const float*)d_in[17];
    const float* biasl   = (const float*)d_in[18];
    const float* gammal  = (const float*)d_in[19];
    const float* betal   = (const float*)d_in[20];
    const float* pp_w1   = (const float*)d_in[21];
    const float* pp_b1   = (const float*)d_in[22];
    const float* pp_w2   = (const float*)d_in[23];
    const float* pp_b2   = (const float*)d_in[24];

    float* ws = (float*)d_ws;
    size_t off = 0;
    f16*   htp    = (f16*)(ws + off); off += 4 * HTSTR / 2;        // 51.2 MB
    f16*   xf     = (f16*)(ws + off); off += (size_t)N_NODES * 64 / 2;
    f16*   Bg2    = (f16*)(ws + off); off += 4 * BGSTR / 2;        // 4.2 MB
    float* agg    = ws + off; off += (size_t)N_NODES * 64;
    float* xa     = ws + off; off += (size_t)N_NODES * 64;
    float* xb     = ws + off; off += (size_t)N_NODES * 64;
    float* stats  = ws + off; off += 4 * 128 + 64;
    float* pooled = ws + off; off += (size_t)NG * 64;
    int*   row_ptr = (int*)(ws + off); off += 10008;
    int*   cursor  = (int*)(ws + off); off += 10000;
    int*   cnt     = (int*)(ws + off); off += 10000;
    int*   eix     = (int*)(ws + off); off += N_EDGES;
    int*   einv    = (int*)(ws + off); off += N_EDGES;
    int*   vn_node = (int*)(ws + off); off += NVMAX + 12;
    int*   vn_rb   = (int*)(ws + off); off += NVMAX + 12;
    int*   nvp     = (int*)(ws + off); off += 8;

    const int eblocks = (N_EDGES + 255) / 256;               // 196
    const int hblocks = (N_EDGES + 127) / 128;               // 391
    const int bblocks = ((8256 << 6) + 255) / 256;           // 2064
    const int fblocks = (NVMAX + BV - 1) / BV;               // 782
    const int ablocks = (N_NODES * 64 + 255) / 256;

    // ---- head: layer-independent work, once
    hipMemsetAsync(pooled, 0, (size_t)NG * 64 * 4, stream);
    hipMemsetAsync(agg, 0, (size_t)N_NODES * 64 * 4, stream);
    hipMemsetAsync(stats, 0, 4 * 128 * 4, stream);
    hipMemsetAsync(cnt, 0, N_NODES * 4, stream);
    csr_count<<<eblocks, 256, 0, stream>>>(src, cnt);
    csr_scan<<<1, 256, 0, stream>>>(cnt, row_ptr, cursor, vn_node, vn_rb, nvp);
    csr_fill<<<eblocks, 256, 0, stream>>>(src, cursor, eix, einv);
    ht_kernel<<<dim3(hblocks, 4), 256, 0, stream>>>(ea, e0w1, e0b1, ew1, eb1,
                                                    einv, htp);
    bconv<<<dim3(bblocks, 4), 256, 0, stream>>>(e0w2, e0b2, ew2, eb2, Bg2);
    xconv<<<(N_NODES * IN0 + 255) / 256, 256, 0, stream>>>(x0, xf, N_NODES * IN0);

    struct Layer {
        const float *root, *bias, *gamma, *beta, *xin;
        float* xout; int in, inshift, mode;
    };
    Layer L[4];
    L[0] = {root0, bias0, gamma0, beta0, x0, xa, IN0, 5, 0};
    for (int l = 0; l < 3; l++) {
        const float* xin  = (l == 0) ? xa : ((l == 1) ? xb : xa);
        float*       xout = (l == 0) ? xb : ((l == 1) ? xa : nullptr);
        L[l + 1] = {rootl + (size_t)l * HID * HID, biasl + (size_t)l * HID,
                    gammal + (size_t)l * HID, betal + (size_t)l * HID,
                    xin, xout, HID, 6, (l == 2) ? 1 : 0};
    }

    // ---- per-layer critical path: fused -> pre_stats -> bn_apply
    for (int l = 0; l < 4; l++) {
        const Layer& P = L[l];
        fused_msg2<<<dim3(fblocks, 2), 512, 0, stream>>>(htp + (size_t)l * HTSTR, xf,
                                                         Bg2 + (size_t)l * BGSTR, eix,
                                                         row_ptr, vn_node, vn_rb, dst,
                                                         agg, nvp, P.inshift);
        pre_stats<<<512, 256, 0, stream>>>(agg, P.xin, P.root, P.bias, agg,
                                           stats + l * 128, P.in, P.inshift);
        bn_apply<<<ablocks, 256, 0, stream>>>(agg, stats + l * 128, P.gamma,
                                              P.beta, P.xout, xf, batch, pooled,
                                              P.mode);
    }
    final_mlp<<<NG, 64, 0, stream>>>(pooled, u, pp_w1, pp_b1, pp_w2, pp_b2,
                                     (float*)d_out);
}

// Round 15
// 669.197 us; speedup vs baseline: 1.2769x; 1.1116x over previous
//
#include <hip/hip_runtime.h>

#define N_NODES 10000
#define N_EDGES 50000
#define IN0     32
#define EDGE_IN 16
#define GIN     8
#define HID     64
#define NG      64
#define KDIM    128
#define BV      16        // virtual nodes per fused block
#define NVMAX   12500     // sum ceil(deg/16) <= (E + 15*N)/16
#define EPS     1e-5f

typedef _Float16 f16;
typedef _Float16 v8h __attribute__((ext_vector_type(8)));
typedef float    v4f __attribute__((ext_vector_type(4)));

#define HTSTR ((size_t)N_EDGES * KDIM)      // per-layer htp stride (f16)
#define BGSTR ((size_t)8256 * 64)           // per-layer Bg2 stride (f16)

// ---------------------------------------------------------------------------
// ALL 4 LAYERS in one dispatch (blockIdx.y = layer). htp[l][e][j] =
// f16(relu(ea[e]@w1_l[:,j] + b1_l[j])) -- LINEAR rows (no einv scatter: fused
// gathers per-lane 16B rows anyway, so the permuted scatter bought nothing and
// cost a 51MB random-write pass). w1/b1/ea staged in LDS; hot loop is
// register/LDS-broadcast only.
__global__ __launch_bounds__(256) void ht_kernel(const float* __restrict__ ea,
                                                 const float* __restrict__ e0w1,
                                                 const float* __restrict__ e0b1,
                                                 const float* __restrict__ ew1,
                                                 const float* __restrict__ eb1,
                                                 f16* __restrict__ htp) {
    const int l = blockIdx.y;
    const float* w1 = (l == 0) ? e0w1 : ew1 + (size_t)(l - 1) * EDGE_IN * KDIM;
    const float* b1 = (l == 0) ? e0b1 : eb1 + (size_t)(l - 1) * KDIM;
    f16* out = htp + (size_t)l * HTSTR;

    __shared__ float w1s[EDGE_IN][KDIM + 1];   // 8.3 KB
    __shared__ float b1s[KDIM];                // 0.5 KB
    __shared__ float eas[128][17];             // 8.7 KB
    __shared__ f16 hl[128][136];               // 34.8 KB
    const int e0 = blockIdx.x * 128, t = threadIdx.x;
    for (int idx = t; idx < EDGE_IN * KDIM; idx += 256)
        w1s[idx >> 7][idx & 127] = w1[idx];
    if (t < KDIM) b1s[t] = b1[t];
    for (int idx = t; idx < 128 * 16; idx += 256) {
        int r = idx >> 4, i = idx & 15;
        eas[r][i] = (e0 + r < N_EDGES) ? ea[(size_t)(e0 + r) * EDGE_IN + i] : 0.f;
    }
    __syncthreads();
    const int el = t & 127, jh = t >> 7;
    float ear[EDGE_IN];
#pragma unroll
    for (int i = 0; i < EDGE_IN; i++) ear[i] = eas[el][i];
#pragma unroll 4
    for (int jj = 0; jj < 64; jj++) {
        const int j = jh * 64 + jj;
        float a0 = b1s[j], a1 = 0.f;
#pragma unroll
        for (int i = 0; i < EDGE_IN; i += 2) {
            a0 += ear[i]     * w1s[i][j];
            a1 += ear[i + 1] * w1s[i + 1][j];
        }
        hl[el][j] = (f16)fmaxf(a0 + a1, 0.f);
    }
    __syncthreads();
    for (int idx = t; idx < 128 * 16; idx += 256) {     // 16 uint4 per 128-f16 row
        const int row = idx >> 4, sg = idx & 15;
        if (e0 + row < N_EDGES) {
            uint4* dp = (uint4*)(out + (size_t)(e0 + row) * KDIM) + sg;
            *dp = *((const uint4*)(&hl[row][0]) + sg);
        }
    }
}

// ---------------------------------------------------------------------------
// xf[idx] = f16(x[idx])   (layer 0 input only; later layers get xf from bn_apply)
__global__ __launch_bounds__(256) void xconv(const float* __restrict__ x,
                                             f16* __restrict__ xf, int n) {
    int idx = blockIdx.x * 256 + threadIdx.x;
    if (idx < n) xf[idx] = (f16)x[idx];
}

// ---------------------------------------------------------------------------
// ALL 4 LAYERS in one dispatch (blockIdx.y = layer).
// Bg2[l][C'][i], C' = o*128 + k (k minor) for k<128: w2_l[k][i*64+o];
// rows 8192+o: b2_l[i*64+o] (the per-node bias term ub). f16.
__global__ __launch_bounds__(256) void bconv(const float* __restrict__ e0w2,
                                             const float* __restrict__ e0b2,
                                             const float* __restrict__ ew2,
                                             const float* __restrict__ eb2,
                                             f16* __restrict__ Bg2all) {
    const int l = blockIdx.y;
    const int inshift = l ? 6 : 5;
    const int in = 1 << inshift;
    const float* w2 = (l == 0) ? e0w2 : ew2 + (size_t)(l - 1) * KDIM * HID * HID;
    const float* b2 = (l == 0) ? e0b2 : eb2 + (size_t)(l - 1) * HID * HID;
    f16* Bg2 = Bg2all + (size_t)l * BGSTR;

    const int total = 8256 << inshift;
    int idx = blockIdx.x * 256 + threadIdx.x;
    if (idx >= total) return;
    const int i = idx & (in - 1), C = idx >> inshift;
    float v;
    if (C < 8192) {
        const int k = C & 127, o = C >> 7;
        v = w2[(size_t)k * (in << 6) + (i << 6) + o];
    } else {
        const int o = C - 8192;
        v = b2[(i << 6) + o];
    }
    Bg2[idx] = (f16)v;
}

// ---------------------------------------------------------------------------
// CSR over SRC (constant across layers; built once) + virtual-node list:
// vnode = (node, 16-edge subrange). nv <= NVMAX.
__global__ __launch_bounds__(256) void csr_count(const int* __restrict__ src,
                                                 int* __restrict__ cnt) {
    int e = blockIdx.x * 256 + threadIdx.x;
    if (e < N_EDGES) atomicAdd(&cnt[src[e]], 1);
}

__global__ __launch_bounds__(256) void csr_scan(const int* __restrict__ cnt,
                                                int* __restrict__ row_ptr,
                                                int* __restrict__ cursor,
                                                int* __restrict__ vn_node,
                                                int* __restrict__ vn_rb,
                                                int* __restrict__ nvp) {
    __shared__ int part[256], psum[257];
    __shared__ int vpart[256], vpsum[257];
    const int t = threadIdx.x;
    const int base = t * 40;                       // 256*40 >= 10000
    int s = 0, vs = 0;
    for (int i = 0; i < 40; i++) {
        int idx = base + i;
        if (idx < N_NODES) { int d = cnt[idx]; s += d; vs += (d + 15) >> 4; }
    }
    part[t] = s; vpart[t] = vs;
    __syncthreads();
    if (t == 0) {
        int run = 0, vrun = 0;
        for (int i = 0; i < 256; i++) {
            psum[i] = run;  run += part[i];
            vpsum[i] = vrun; vrun += vpart[i];
        }
        psum[256] = run; vpsum[256] = vrun;
    }
    __syncthreads();
    int run = psum[t], vrun = vpsum[t];
    for (int i = 0; i < 40; i++) {
        int idx = base + i;
        if (idx < N_NODES) {
            int d = cnt[idx];
            row_ptr[idx] = run; cursor[idx] = run;
            int nvn = (d + 15) >> 4;
            for (int j = 0; j < nvn; j++) {
                vn_node[vrun] = idx; vn_rb[vrun] = run + j * 16; vrun++;
            }
            run += d;
        }
    }
    if (t == 255) { row_ptr[N_NODES] = psum[256]; *nvp = vpsum[256]; }
}

__global__ __launch_bounds__(256) void csr_fill(const int* __restrict__ src,
                                                int* __restrict__ cursor,
                                                int* __restrict__ eix) {
    int e = blockIdx.x * 256 + threadIdx.x;
    if (e < N_EDGES) {
        int p = atomicAdd(&cursor[src[e]], 1);
        eix[p] = e;
    }
}

// ---------------------------------------------------------------------------
// Node-factored NNConv. R14 structure (512 thr, K-split=2) + two changes:
// (1) T-phase loads batched 4-deep into explicit arrays -- R14's VGPR=52 left
//     ~4 regs for load buffers, serializing the 16 L2 loads/chunk one-at-a-time
//     (~200cy each, barrier-coupled). launch_bounds(512,4) caps VGPR at 128.
// (2) htp rows are linear; gather via eix (ht's einv scatter removed).
//   T[n,k,o] = sum_i xf[n,i] * w2[k,i,o]
//   msg[e,o] = sum_k ht[e,k] * T[src,k,o] + ub[src,o];  agg[dst] += msg
__global__ __launch_bounds__(512, 4) void fused_msg2(const f16* __restrict__ htp,
                                                     const f16* __restrict__ xf,
                                                     const f16* __restrict__ Bg2,
                                                     const int* __restrict__ eix,
                                                     const int* __restrict__ row_ptr,
                                                     const int* __restrict__ vn_node,
                                                     const int* __restrict__ vn_rb,
                                                     const int* __restrict__ dst,
                                                     float* __restrict__ agg,
                                                     const int* __restrict__ nvp,
                                                     int inshift) {
    __shared__ f16 tcs[BV * 1024 + 32];   // [slot][(o^(slot&3))][k16] + tail pad
    __shared__ f16 ubs[BV * 68];          // [slot][o] row-padded 64->68
    __shared__ int snd[BV], srb[BV], sct[BV];

    const int t = threadIdx.x;
    const int w = t >> 6, lane = t & 63;  // w = 0..7
    const int m = lane & 15, q = lane >> 4;
    const int v0 = blockIdx.x * BV;
    const int nv = *nvp;
    if (v0 >= nv) return;
    const bool in64 = (inshift == 6);
    const int cbeg = blockIdx.y * 4, cend = cbeg + 4;   // K-segment (4 chunks)

    if (t < BV) {
        int v = v0 + t, n = 0, rb = 0, ct = 0;
        if (v < nv) {
            n = vn_node[v]; rb = vn_rb[v];
            int re = row_ptr[n + 1];
            ct = re - rb; if (ct > 16) ct = 16;
        }
        snd[t] = n; srb[t] = rb; sct[t] = ct;
    }
    // zero the tail pad (vn=BV-1, q>=2 lanes read it with zero-A; stale NaN
    // would poison 0*x)
    if (t >= 32 && t < 40) *(uint2*)(tcs + BV * 1024 + (t - 32) * 4) = (uint2){0u, 0u};
    __syncthreads();

    // T-phase B-fragment: xf row of slot m (N dim = the 16 slots)
    v8h bfx[2];
    {
        const size_t nb = (size_t)snd[m] << inshift;
        bfx[0] = *(const v8h*)(xf + nb + q * 8);
        if (in64) bfx[1] = *(const v8h*)(xf + nb + 32 + q * 8);
    }

    // chunk-invariant htp row pointer per j (this lane's edge slot of vnode,
    // gathered through eix -- htp rows are linear now)
    const f16* hrow[2];
#pragma unroll
    for (int j = 0; j < 2; j++) {
        const int vn = (w << 1) + j;
        const int rb = srb[vn], ct = sct[vn];
        const int es = (m < ct) ? m : (ct > 0 ? ct - 1 : 0);
        hrow[j] = htp + (size_t)eix[rb + es] * KDIM;
    }

    v4f acc[2][4];
#pragma unroll
    for (int j = 0; j < 2; j++)
#pragma unroll
        for (int ot = 0; ot < 4; ot++) acc[j][ot] = (v4f){0.f, 0.f, 0.f, 0.f};

    for (int c = cbeg; c < cend; c++) {
        // ---- prefetch this chunk's app-phase ht fragments
        v8h hpre[2];
#pragma unroll
        for (int j = 0; j < 2; j++) {
            v8h tmp;
#pragma unroll
            for (int z = 0; z < 8; z++) tmp[z] = (f16)0.f;
            if (q < 2)      // lanes q>=2 are k 16..31 of the MFMA: zero (K=16 pad)
                tmp = *(const v8h*)(hrow[j] + (c << 4) + q * 8);
            hpre[j] = tmp;
        }
        // ---- T-phase: wave w computes o in [w*8, w*8+8), all 16 slots.
        // Loads issued in 4-deep batches (explicit arrays) so 4-8 L2 requests
        // are in flight instead of 1.
#pragma unroll
        for (int half = 0; half < 2; half++) {
            v8h a0[4], a1[4];
#pragma unroll
            for (int ol = 0; ol < 4; ol++) {
                const int o = (w << 3) + (half << 2) + ol;
                const size_t arow = ((size_t)(o * 128 + (c << 4) + m)) << inshift;
                a0[ol] = *(const v8h*)(Bg2 + arow + q * 8);
                if (in64) a1[ol] = *(const v8h*)(Bg2 + arow + 32 + q * 8);
            }
#pragma unroll
            for (int ol = 0; ol < 4; ol++) {
                const int o = (w << 3) + (half << 2) + ol;
                v4f d = (v4f){0.f, 0.f, 0.f, 0.f};
                d = __builtin_amdgcn_mfma_f32_16x16x32_f16(a0[ol], bfx[0], d, 0, 0, 0);
                if (in64)
                    d = __builtin_amdgcn_mfma_f32_16x16x32_f16(a1[ol], bfx[1], d, 0, 0, 0);
                const int sl = m;                     // SLOT index
                union { f16 x[4]; uint2 u; } pk;
                pk.x[0] = (f16)d[0]; pk.x[1] = (f16)d[1];
                pk.x[2] = (f16)d[2]; pk.x[3] = (f16)d[3];
                *(uint2*)(tcs + sl * 1024 + ((o ^ (sl & 3)) << 4) + (q << 2)) = pk.u;
            }
        }
        __syncthreads();
        // ---- app-phase: wave w applies vnode slots w*2 .. w*2+1
#pragma unroll
        for (int j = 0; j < 2; j++) {
            const int vn = (w << 1) + j;              // SLOT index 0..15
            const f16* tb = tcs + vn * 1024;
            const int nx = vn & 3;
#pragma unroll
            for (int ot = 0; ot < 4; ot++) {
                v8h hb = *(const v8h*)(tb + ((((ot << 4) + m) ^ nx) << 4) + (q << 3));
                acc[j][ot] = __builtin_amdgcn_mfma_f32_16x16x32_f16(hpre[j], hb,
                                                                    acc[j][ot], 0, 0, 0);
            }
        }
        __syncthreads();
    }

    // ---- ub mini-chunk (segment 0, waves 0-3): ub[slot][o] = xf[n,:]@b2[:,o]
    if (blockIdx.y == 0 && w < 4) {
        const size_t arow = ((size_t)(8192 + (w << 4) + m)) << inshift;
        v8h a0 = *(const v8h*)(Bg2 + arow + q * 8);
        v4f d = (v4f){0.f, 0.f, 0.f, 0.f};
        d = __builtin_amdgcn_mfma_f32_16x16x32_f16(a0, bfx[0], d, 0, 0, 0);
        if (in64) {
            v8h a1 = *(const v8h*)(Bg2 + arow + 32 + q * 8);
            d = __builtin_amdgcn_mfma_f32_16x16x32_f16(a1, bfx[1], d, 0, 0, 0);
        }
        const int sl = m;                             // SLOT index
        union { f16 x[4]; uint2 u; } pk;
        pk.x[0] = (f16)d[0]; pk.x[1] = (f16)d[1];
        pk.x[2] = (f16)d[2]; pk.x[3] = (f16)d[3];
        *(uint2*)(ubs + sl * 68 + (w << 4) + (q << 2)) = pk.u;
    }
    __syncthreads();

    // ---- epilogue: scatter acc (+ ub for segment 0) into agg by dst
#pragma unroll
    for (int j = 0; j < 2; j++) {
        const int vn = (w << 1) + j;                  // SLOT index
        const int rb = srb[vn], ct = sct[vn];
        if (ct == 0) continue;                        // wave-uniform
        int dr[4];
#pragma unroll
        for (int r = 0; r < 4; r++) {
            const int es = (q << 2) + r;
            dr[r] = (es < ct) ? dst[eix[rb + es]] : -1;
        }
#pragma unroll
        for (int ot = 0; ot < 4; ot++) {
            float ub = 0.f;
            if (blockIdx.y == 0) ub = (float)ubs[vn * 68 + (ot << 4) + m];
#pragma unroll
            for (int r = 0; r < 4; r++)
                if (dr[r] >= 0)
                    atomicAdd(&agg[(size_t)dr[r] * 64 + (ot << 4) + m],
                              acc[j][ot][r] + ub);
        }
    }
}

// ---------------------------------------------------------------------------
// pre[n,o] = agg[n,o] + sum_i x[n,i]*root[i,o] + bias[o]; accumulate BN stats.
// root staged in LDS ONCE (R14's version re-read root from global inside the
// 64-iter inner loop -- the same lgkmcnt serialization ht_kernel had).
__global__ __launch_bounds__(256) void pre_stats(const float* __restrict__ agg,
                                                 const float* __restrict__ x,
                                                 const float* __restrict__ root,
                                                 const float* __restrict__ bias,
                                                 float* __restrict__ pre,
                                                 float* __restrict__ stats,
                                                 int in, int inshift) {
    __shared__ float rs[64 * 65];      // [i][o] padded row 64->65 (16.6 KB max)
    __shared__ float xs[4][64];
    __shared__ float lsum[64], lsq[64];
    const int o = threadIdx.x & 63, nl = threadIdx.x >> 6;
    if (threadIdx.x < 64) { lsum[threadIdx.x] = 0.f; lsq[threadIdx.x] = 0.f; }
    for (int idx = threadIdx.x; idx < (in << 6); idx += 256)
        rs[(idx >> 6) * 65 + (idx & 63)] = root[idx];
    const float bo = bias[o];
    for (int n0 = blockIdx.x * 4; n0 < N_NODES; n0 += gridDim.x * 4) {
        __syncthreads();
        for (int idx = threadIdx.x; idx < (4 << inshift); idx += 256) {
            int r = idx >> inshift, i = idx & (in - 1);
            if (n0 + r < N_NODES) xs[r][i] = x[(size_t)(n0 + r) * in + i];
        }
        __syncthreads();
        int n = n0 + nl;
        if (n < N_NODES) {
            float acc = agg[(size_t)n * 64 + o] + bo;
#pragma unroll 8
            for (int i = 0; i < in; i++) acc += xs[nl][i] * rs[i * 65 + o];
            pre[(size_t)n * 64 + o] = acc;
            atomicAdd(&lsum[o], acc);
            atomicAdd(&lsq[o], acc * acc);
        }
    }
    __syncthreads();
    if (threadIdx.x < 64) {
        atomicAdd(&stats[threadIdx.x], lsum[threadIdx.x]);
        atomicAdd(&stats[64 + threadIdx.x], lsq[threadIdx.x]);
    }
}

// ---------------------------------------------------------------------------
// BN (batch stats, biased var) + ReLU. Zeroes pre(=agg) after its single read
// (replaces the per-layer agg memset). mode 0: store xn (f32) + xf (f16, input
// to next layer's fused T-phase). mode 1: segment-max pool.
__global__ __launch_bounds__(256) void bn_apply(float* __restrict__ pre,
                                                const float* __restrict__ stats,
                                                const float* __restrict__ gamma,
                                                const float* __restrict__ beta,
                                                float* __restrict__ xn,
                                                f16* __restrict__ xfo,
                                                const int* __restrict__ batch,
                                                float* __restrict__ pooled,
                                                int mode) {
    int idx = blockIdx.x * 256 + threadIdx.x;
    if (idx >= N_NODES * 64) return;
    const int o = idx & 63, n = idx >> 6;
    const float inv = 1.f / (float)N_NODES;
    float mu = stats[o] * inv;
    float var = stats[64 + o] * inv - mu * mu;
    float sc = gamma[o] * rsqrtf(var + EPS);
    float sh = beta[o] - mu * sc;
    float p = pre[idx];
    pre[idx] = 0.f;                     // agg zeroed for the next layer's fused
    float v = fmaxf(p * sc + sh, 0.f);
    if (mode == 0) { xn[idx] = v; xfo[idx] = (f16)v; }
    else atomicMax((int*)&pooled[(size_t)batch[n] * 64 + o], __float_as_int(v));
}

// ---------------------------------------------------------------------------
// out[g] = pp_b2 + relu(cat(pooled[g],u[g]) @ pp_w1 + pp_b1) @ pp_w2
__global__ __launch_bounds__(64) void final_mlp(const float* __restrict__ pooled,
                                                const float* __restrict__ u,
                                                const float* __restrict__ w1,
                                                const float* __restrict__ b1,
                                                const float* __restrict__ w2,
                                                const float* __restrict__ b2,
                                                float* __restrict__ out) {
    const int g = blockIdx.x, t = threadIdx.x;
    float acc = b1[t];
#pragma unroll 8
    for (int i = 0; i < 64; i++) acc += pooled[g * 64 + i] * w1[i * 64 + t];
#pragma unroll
    for (int j = 0; j < GIN; j++) acc += u[g * GIN + j] * w1[(64 + j) * 64 + t];
    float hv = fmaxf(acc, 0.f) * w2[t];
#pragma unroll
    for (int off = 32; off > 0; off >>= 1) hv += __shfl_down(hv, off, 64);
    if (t == 0) out[g] = hv + b2[0];
}

// ---------------------------------------------------------------------------
extern "C" void kernel_launch(void* const* d_in, const int* in_sizes, int n_in,
                              void* d_out, int out_size, void* d_ws, size_t ws_size,
                              hipStream_t stream) {
    const float* x0      = (const float*)d_in[0];
    const int*   ei      = (const int*)d_in[1];
    const int*   src     = ei;
    const int*   dst     = ei + N_EDGES;
    const float* ea      = (const float*)d_in[2];
    const int*   batch   = (const int*)d_in[3];
    const float* u       = (const float*)d_in[4];
    const float* e0w1    = (const float*)d_in[5];
    const float* e0b1    = (const float*)d_in[6];
    const float* e0w2    = (const float*)d_in[7];
    const float* e0b2    = (const float*)d_in[8];
    const float* root0   = (const float*)d_in[9];
    const float* bias0   = (const float*)d_in[10];
    const float* gamma0  = (const float*)d_in[11];
    const float* beta0   = (const float*)d_in[12];
    const float* ew1     = (const float*)d_in[13];
    const float* eb1     = (const float*)d_in[14];
    const float* ew2     = (const float*)d_in[15];
    const float* eb2     = (const float*)d_in[16];
    const float* rootl   = (const float*)d_in[17];
    const float* biasl   = (const float*)d_in[18];
    const float* gammal  = (const float*)d_in[19];
    const float* betal   = (const float*)d_in[20];
    const float* pp_w1   = (const float*)d_in[21];
    const float* pp_b1   = (const float*)d_in[22];
    const float* pp_w2   = (const float*)d_in[23];
    const float* pp_b2   = (const float*)d_in[24];

    float* ws = (float*)d_ws;
    size_t off = 0;
    f16*   htp    = (f16*)(ws + off); off += 4 * HTSTR / 2;        // 51.2 MB
    f16*   xf     = (f16*)(ws + off); off += (size_t)N_NODES * 64 / 2;
    f16*   Bg2    = (f16*)(ws + off); off += 4 * BGSTR / 2;        // 4.2 MB
    float* agg    = ws + off; off += (size_t)N_NODES * 64;
    float* xa     = ws + off; off += (size_t)N_NODES * 64;
    float* xb     = ws + off; off += (size_t)N_NODES * 64;
    float* stats  = ws + off; off += 4 * 128 + 64;
    float* pooled = ws + off; off += (size_t)NG * 64;
    int*   row_ptr = (int*)(ws + off); off += 10008;
    int*   cursor  = (int*)(ws + off); off += 10000;
    int*   cnt     = (int*)(ws + off); off += 10000;
    int*   eix     = (int*)(ws + off); off += N_EDGES;
    int*   vn_node = (int*)(ws + off); off += NVMAX + 12;
    int*   vn_rb   = (int*)(ws + off); off += NVMAX + 12;
    int*   nvp     = (int*)(ws + off); off += 8;

    const int eblocks = (N_EDGES + 255) / 256;               // 196
    const int hblocks = (N_EDGES + 127) / 128;               // 391
    const int bblocks = ((8256 << 6) + 255) / 256;           // 2064
    const int fblocks = (NVMAX + BV - 1) / BV;               // 782
    const int ablocks = (N_NODES * 64 + 255) / 256;

    // ---- head: layer-independent work, once
    hipMemsetAsync(pooled, 0, (size_t)NG * 64 * 4, stream);
    hipMemsetAsync(agg, 0, (size_t)N_NODES * 64 * 4, stream);
    hipMemsetAsync(stats, 0, 4 * 128 * 4, stream);
    hipMemsetAsync(cnt, 0, N_NODES * 4, stream);
    csr_count<<<eblocks, 256, 0, stream>>>(src, cnt);
    csr_scan<<<1, 256, 0, stream>>>(cnt, row_ptr, cursor, vn_node, vn_rb, nvp);
    csr_fill<<<eblocks, 256, 0, stream>>>(src, cursor, eix);
    ht_kernel<<<dim3(hblocks, 4), 256, 0, stream>>>(ea, e0w1, e0b1, ew1, eb1, htp);
    bconv<<<dim3(bblocks, 4), 256, 0, stream>>>(e0w2, e0b2, ew2, eb2, Bg2);
    xconv<<<(N_NODES * IN0 + 255) / 256, 256, 0, stream>>>(x0, xf, N_NODES * IN0);

    struct Layer {
        const float *root, *bias, *gamma, *beta, *xin;
        float* xout; int in, inshift, mode;
    };
    Layer L[4];
    L[0] = {root0, bias0, gamma0, beta0, x0, xa, IN0, 5, 0};
    for (int l = 0; l < 3; l++) {
        const float* xin  = (l == 0) ? xa : ((l == 1) ? xb : xa);
        float*       xout = (l == 0) ? xb : ((l == 1) ? xa : nullptr);
        L[l + 1] = {rootl + (size_t)l * HID * HID, biasl + (size_t)l * HID,
                    gammal + (size_t)l * HID, betal + (size_t)l * HID,
                    xin, xout, HID, 6, (l == 2) ? 1 : 0};
    }

    // ---- per-layer critical path: fused -> pre_stats -> bn_apply
    for (int l = 0; l < 4; l++) {
        const Layer& P = L[l];
        fused_msg2<<<dim3(fblocks, 2), 512, 0, stream>>>(htp + (size_t)l * HTSTR, xf,
                                                         Bg2 + (size_t)l * BGSTR, eix,
                                                         row_ptr, vn_node, vn_rb, dst,
                                                         agg, nvp, P.inshift);
        pre_stats<<<512, 256, 0, stream>>>(agg, P.xin, P.root, P.bias, agg,
                                           stats + l * 128, P.in, P.inshift);
        bn_apply<<<ablocks, 256, 0, stream>>>(agg, stats + l * 128, P.gamma,
                                              P.beta, P.xout, xf, batch, pooled,
                                              P.mode);
    }
    final_mlp<<<NG, 64, 0, stream>>>(pooled, u, pp_w1, pp_b1, pp_w2, pp_b2,
                                     (float*)d_out);
}

// Round 16
// 520.891 us; speedup vs baseline: 1.6405x; 1.2847x over previous
//
#include <hip/hip_runtime.h>

#define N_NODES 10000
#define N_EDGES 50000
#define IN0     32
#define EDGE_IN 16
#define GIN     8
#define HID     64
#define NG      64
#define KDIM    128
#define BV      16        // virtual nodes per fused block
#define NVMAX   12500     // sum ceil(deg/16) <= (E + 15*N)/16
#define EPS     1e-5f

typedef _Float16 f16;
typedef _Float16 v8h __attribute__((ext_vector_type(8)));
typedef float    v4f __attribute__((ext_vector_type(4)));

#define HTSTR ((size_t)N_EDGES * KDIM)      // per-layer htp stride (f16)
#define BGSTR ((size_t)8256 * 64)           // per-layer Bg2 stride (f16)

// ---------------------------------------------------------------------------
// ALL 4 LAYERS in one dispatch (blockIdx.y = layer). htp[l][e][j] =
// f16(relu(ea[e]@w1_l[:,j] + b1_l[j])) -- linear rows; fused gathers via eix.
__global__ __launch_bounds__(256) void ht_kernel(const float* __restrict__ ea,
                                                 const float* __restrict__ e0w1,
                                                 const float* __restrict__ e0b1,
                                                 const float* __restrict__ ew1,
                                                 const float* __restrict__ eb1,
                                                 f16* __restrict__ htp) {
    const int l = blockIdx.y;
    const float* w1 = (l == 0) ? e0w1 : ew1 + (size_t)(l - 1) * EDGE_IN * KDIM;
    const float* b1 = (l == 0) ? e0b1 : eb1 + (size_t)(l - 1) * KDIM;
    f16* out = htp + (size_t)l * HTSTR;

    __shared__ float w1s[EDGE_IN][KDIM + 1];   // 8.3 KB
    __shared__ float b1s[KDIM];                // 0.5 KB
    __shared__ float eas[128][17];             // 8.7 KB
    __shared__ f16 hl[128][136];               // 34.8 KB
    const int e0 = blockIdx.x * 128, t = threadIdx.x;
    for (int idx = t; idx < EDGE_IN * KDIM; idx += 256)
        w1s[idx >> 7][idx & 127] = w1[idx];
    if (t < KDIM) b1s[t] = b1[t];
    for (int idx = t; idx < 128 * 16; idx += 256) {
        int r = idx >> 4, i = idx & 15;
        eas[r][i] = (e0 + r < N_EDGES) ? ea[(size_t)(e0 + r) * EDGE_IN + i] : 0.f;
    }
    __syncthreads();
    const int el = t & 127, jh = t >> 7;
    float ear[EDGE_IN];
#pragma unroll
    for (int i = 0; i < EDGE_IN; i++) ear[i] = eas[el][i];
#pragma unroll 4
    for (int jj = 0; jj < 64; jj++) {
        const int j = jh * 64 + jj;
        float a0 = b1s[j], a1 = 0.f;
#pragma unroll
        for (int i = 0; i < EDGE_IN; i += 2) {
            a0 += ear[i]     * w1s[i][j];
            a1 += ear[i + 1] * w1s[i + 1][j];
        }
        hl[el][j] = (f16)fmaxf(a0 + a1, 0.f);
    }
    __syncthreads();
    for (int idx = t; idx < 128 * 16; idx += 256) {     // 16 uint4 per 128-f16 row
        const int row = idx >> 4, sg = idx & 15;
        if (e0 + row < N_EDGES) {
            uint4* dp = (uint4*)(out + (size_t)(e0 + row) * KDIM) + sg;
            *dp = *((const uint4*)(&hl[row][0]) + sg);
        }
    }
}

// ---------------------------------------------------------------------------
// xf[idx] = f16(x[idx])   (layer 0 input only; later layers get xf from bn_apply)
__global__ __launch_bounds__(256) void xconv(const float* __restrict__ x,
                                             f16* __restrict__ xf, int n) {
    int idx = blockIdx.x * 256 + threadIdx.x;
    if (idx < n) xf[idx] = (f16)x[idx];
}

// ---------------------------------------------------------------------------
// ALL 4 LAYERS in one dispatch (blockIdx.y = layer).
// WAVE-CONTIGUOUS Bg2 layout (kills the T-phase 16-line-per-load TA cost):
// Region A (idx < 8192*in): chunk-blocks CB(o,c) of 16*in f16. Within a CB,
//   lane (m,q)'s 8-f16 fragment is CONTIGUOUS at (half*512 if in64) +
//   ((q*16+m)*8). Value = w2[k=c*16+m][i*64+o], i = half*32 + q*8 + j.
// Region B (ub): at 8192*in, row o (64 rows) x in: b2[i*64+o].
__global__ __launch_bounds__(256) void bconv(const float* __restrict__ e0w2,
                                             const float* __restrict__ e0b2,
                                             const float* __restrict__ ew2,
                                             const float* __restrict__ eb2,
                                             f16* __restrict__ Bg2all) {
    const int l = blockIdx.y;
    const int inshift = l ? 6 : 5;
    const int in = 1 << inshift;
    const float* w2 = (l == 0) ? e0w2 : ew2 + (size_t)(l - 1) * KDIM * HID * HID;
    const float* b2 = (l == 0) ? e0b2 : eb2 + (size_t)(l - 1) * HID * HID;
    f16* Bg2 = Bg2all + (size_t)l * BGSTR;

    const int total = 8256 << inshift;
    int idx = blockIdx.x * 256 + threadIdx.x;
    if (idx >= total) return;
    const int regA = 8192 << inshift;
    float v;
    if (idx < regA) {
        const int cbsize = 16 << inshift;              // 512 (in32) / 1024 (in64)
        const int cb = idx / cbsize, r = idx - cb * cbsize;
        int half = 0, rr = r;
        if (inshift == 6 && r >= 512) { half = 1; rr = r - 512; }
        const int j = rr & 7, t2 = rr >> 3;
        const int m = t2 & 15, q = t2 >> 4;            // q in [0,4)
        const int o = cb >> 3, c = cb & 7;
        const int k = c * 16 + m;
        const int i = half * 32 + q * 8 + j;
        v = w2[(size_t)k * (in << 6) + (i << 6) + o];
    } else {
        const int idx2 = idx - regA;
        const int o = idx2 >> inshift, i = idx2 & (in - 1);
        v = b2[(i << 6) + o];
    }
    Bg2[idx] = (f16)v;
}

// ---------------------------------------------------------------------------
// CSR over SRC (constant across layers; built once) + virtual-node list:
// vnode = (node, 16-edge subrange). nv <= NVMAX.
__global__ __launch_bounds__(256) void csr_count(const int* __restrict__ src,
                                                 int* __restrict__ cnt) {
    int e = blockIdx.x * 256 + threadIdx.x;
    if (e < N_EDGES) atomicAdd(&cnt[src[e]], 1);
}

__global__ __launch_bounds__(256) void csr_scan(const int* __restrict__ cnt,
                                                int* __restrict__ row_ptr,
                                                int* __restrict__ cursor,
                                                int* __restrict__ vn_node,
                                                int* __restrict__ vn_rb,
                                                int* __restrict__ nvp) {
    __shared__ int part[256], psum[257];
    __shared__ int vpart[256], vpsum[257];
    const int t = threadIdx.x;
    const int base = t * 40;                       // 256*40 >= 10000
    int s = 0, vs = 0;
    for (int i = 0; i < 40; i++) {
        int idx = base + i;
        if (idx < N_NODES) { int d = cnt[idx]; s += d; vs += (d + 15) >> 4; }
    }
    part[t] = s; vpart[t] = vs;
    __syncthreads();
    if (t == 0) {
        int run = 0, vrun = 0;
        for (int i = 0; i < 256; i++) {
            psum[i] = run;  run += part[i];
            vpsum[i] = vrun; vrun += vpart[i];
        }
        psum[256] = run; vpsum[256] = vrun;
    }
    __syncthreads();
    int run = psum[t], vrun = vpsum[t];
    for (int i = 0; i < 40; i++) {
        int idx = base + i;
        if (idx < N_NODES) {
            int d = cnt[idx];
            row_ptr[idx] = run; cursor[idx] = run;
            int nvn = (d + 15) >> 4;
            for (int j = 0; j < nvn; j++) {
                vn_node[vrun] = idx; vn_rb[vrun] = run + j * 16; vrun++;
            }
            run += d;
        }
    }
    if (t == 255) { row_ptr[N_NODES] = psum[256]; *nvp = vpsum[256]; }
}

__global__ __launch_bounds__(256) void csr_fill(const int* __restrict__ src,
                                                int* __restrict__ cursor,
                                                int* __restrict__ eix) {
    int e = blockIdx.x * 256 + threadIdx.x;
    if (e < N_EDGES) {
        int p = atomicAdd(&cursor[src[e]], 1);
        eix[p] = e;
    }
}

// ---------------------------------------------------------------------------
// Node-factored NNConv. R15 structure (512 thr, batched loads) with:
// (1) wave-contiguous Bg2 chunk-blocks -- each T-phase load now covers 8
//     consecutive 128B lines (was 16 half-used) => TA/L1 transaction cost
//     halves on the dominant load stream;
// (2) KSEG=1 (R10/R13: unsplit >= split) -- atomics halve, ub always computed.
//   T[n,k,o] = sum_i xf[n,i] * w2[k,i,o]
//   msg[e,o] = sum_k ht[e,k] * T[src,k,o] + ub[src,o];  agg[dst] += msg
__global__ __launch_bounds__(512, 4) void fused_msg2(const f16* __restrict__ htp,
                                                     const f16* __restrict__ xf,
                                                     const f16* __restrict__ Bg2,
                                                     const int* __restrict__ eix,
                                                     const int* __restrict__ row_ptr,
                                                     const int* __restrict__ vn_node,
                                                     const int* __restrict__ vn_rb,
                                                     const int* __restrict__ dst,
                                                     float* __restrict__ agg,
                                                     const int* __restrict__ nvp,
                                                     int inshift) {
    __shared__ f16 tcs[BV * 1024 + 32];   // [slot][(o^(slot&3))][k16] + tail pad
    __shared__ f16 ubs[BV * 68];          // [slot][o] row-padded 64->68
    __shared__ int snd[BV], srb[BV], sct[BV];

    const int t = threadIdx.x;
    const int w = t >> 6, lane = t & 63;  // w = 0..7
    const int m = lane & 15, q = lane >> 4;
    const int v0 = blockIdx.x * BV;
    const int nv = *nvp;
    if (v0 >= nv) return;
    const bool in64 = (inshift == 6);
    const int cbsz = 16 << inshift;       // f16 per chunk-block

    if (t < BV) {
        int v = v0 + t, n = 0, rb = 0, ct = 0;
        if (v < nv) {
            n = vn_node[v]; rb = vn_rb[v];
            int re = row_ptr[n + 1];
            ct = re - rb; if (ct > 16) ct = 16;
        }
        snd[t] = n; srb[t] = rb; sct[t] = ct;
    }
    // zero the tail pad (vn=BV-1, q>=2 lanes read it with zero-A; stale NaN
    // would poison 0*x)
    if (t >= 32 && t < 40) *(uint2*)(tcs + BV * 1024 + (t - 32) * 4) = (uint2){0u, 0u};
    __syncthreads();

    // T-phase B-fragment: xf row of slot m (N dim = the 16 slots)
    v8h bfx[2];
    {
        const size_t nb = (size_t)snd[m] << inshift;
        bfx[0] = *(const v8h*)(xf + nb + q * 8);
        if (in64) bfx[1] = *(const v8h*)(xf + nb + 32 + q * 8);
    }

    // chunk-invariant htp row pointer per j (this lane's edge slot of vnode,
    // gathered through eix -- htp rows are linear)
    const f16* hrow[2];
#pragma unroll
    for (int j = 0; j < 2; j++) {
        const int vn = (w << 1) + j;
        const int rb = srb[vn], ct = sct[vn];
        const int es = (m < ct) ? m : (ct > 0 ? ct - 1 : 0);
        hrow[j] = htp + (size_t)eix[rb + es] * KDIM;
    }

    // per-lane fragment offset inside a chunk-block (contiguous per wave)
    const int fro = ((q << 4) + m) << 3;   // (q*16+m)*8 f16

    v4f acc[2][4];
#pragma unroll
    for (int j = 0; j < 2; j++)
#pragma unroll
        for (int ot = 0; ot < 4; ot++) acc[j][ot] = (v4f){0.f, 0.f, 0.f, 0.f};

    for (int c = 0; c < 8; c++) {
        // ---- prefetch this chunk's app-phase ht fragments
        v8h hpre[2];
#pragma unroll
        for (int j = 0; j < 2; j++) {
            v8h tmp;
#pragma unroll
            for (int z = 0; z < 8; z++) tmp[z] = (f16)0.f;
            if (q < 2)      // lanes q>=2 are k 16..31 of the MFMA: zero (K=16 pad)
                tmp = *(const v8h*)(hrow[j] + (c << 4) + q * 8);
            hpre[j] = tmp;
        }
        // ---- T-phase: wave w computes o in [w*8, w*8+8), all 16 slots.
        // Loads batched 4-deep; each load is a contiguous 1KB wave read.
#pragma unroll
        for (int half = 0; half < 2; half++) {
            v8h a0[4], a1[4];
#pragma unroll
            for (int ol = 0; ol < 4; ol++) {
                const int o = (w << 3) + (half << 2) + ol;
                const f16* cbb = Bg2 + (size_t)((o << 3) + c) * cbsz;
                a0[ol] = *(const v8h*)(cbb + fro);
                if (in64) a1[ol] = *(const v8h*)(cbb + 512 + fro);
            }
#pragma unroll
            for (int ol = 0; ol < 4; ol++) {
                const int o = (w << 3) + (half << 2) + ol;
                v4f d = (v4f){0.f, 0.f, 0.f, 0.f};
                d = __builtin_amdgcn_mfma_f32_16x16x32_f16(a0[ol], bfx[0], d, 0, 0, 0);
                if (in64)
                    d = __builtin_amdgcn_mfma_f32_16x16x32_f16(a1[ol], bfx[1], d, 0, 0, 0);
                const int sl = m;                     // SLOT index
                union { f16 x[4]; uint2 u; } pk;
                pk.x[0] = (f16)d[0]; pk.x[1] = (f16)d[1];
                pk.x[2] = (f16)d[2]; pk.x[3] = (f16)d[3];
                *(uint2*)(tcs + sl * 1024 + ((o ^ (sl & 3)) << 4) + (q << 2)) = pk.u;
            }
        }
        __syncthreads();
        // ---- app-phase: wave w applies vnode slots w*2 .. w*2+1
#pragma unroll
        for (int j = 0; j < 2; j++) {
            const int vn = (w << 1) + j;              // SLOT index 0..15
            const f16* tb = tcs + vn * 1024;
            const int nx = vn & 3;
#pragma unroll
            for (int ot = 0; ot < 4; ot++) {
                v8h hb = *(const v8h*)(tb + ((((ot << 4) + m) ^ nx) << 4) + (q << 3));
                acc[j][ot] = __builtin_amdgcn_mfma_f32_16x16x32_f16(hpre[j], hb,
                                                                    acc[j][ot], 0, 0, 0);
            }
        }
        __syncthreads();
    }

    // ---- ub mini-chunk (waves 0-3): ub[slot][o] = xf[n,:]@b2[:,o]
    // Region B rows: Bg2[8192*in + o'*in + i], A-row o' = w*16+m.
    if (w < 4) {
        const f16* ubb = Bg2 + ((size_t)8192 << inshift) +
                         ((size_t)((w << 4) + m) << inshift);
        v8h a0 = *(const v8h*)(ubb + q * 8);
        v4f d = (v4f){0.f, 0.f, 0.f, 0.f};
        d = __builtin_amdgcn_mfma_f32_16x16x32_f16(a0, bfx[0], d, 0, 0, 0);
        if (in64) {
            v8h a1 = *(const v8h*)(ubb + 32 + q * 8);
            d = __builtin_amdgcn_mfma_f32_16x16x32_f16(a1, bfx[1], d, 0, 0, 0);
        }
        const int sl = m;                             // SLOT index
        union { f16 x[4]; uint2 u; } pk;
        pk.x[0] = (f16)d[0]; pk.x[1] = (f16)d[1];
        pk.x[2] = (f16)d[2]; pk.x[3] = (f16)d[3];
        *(uint2*)(ubs + sl * 68 + (w << 4) + (q << 2)) = pk.u;
    }
    __syncthreads();

    // ---- epilogue: scatter acc + ub into agg by dst (f32 atomics)
#pragma unroll
    for (int j = 0; j < 2; j++) {
        const int vn = (w << 1) + j;                  // SLOT index
        const int rb = srb[vn], ct = sct[vn];
        if (ct == 0) continue;                        // wave-uniform
        int dr[4];
#pragma unroll
        for (int r = 0; r < 4; r++) {
            const int es = (q << 2) + r;
            dr[r] = (es < ct) ? dst[eix[rb + es]] : -1;
        }
#pragma unroll
        for (int ot = 0; ot < 4; ot++) {
            const float ub = (float)ubs[vn * 68 + (ot << 4) + m];
#pragma unroll
            for (int r = 0; r < 4; r++)
                if (dr[r] >= 0)
                    atomicAdd(&agg[(size_t)dr[r] * 64 + (ot << 4) + m],
                              acc[j][ot][r] + ub);
        }
    }
}

// ---------------------------------------------------------------------------
// pre[n,o] = agg[n,o] + sum_i x[n,i]*root[i,o] + bias[o]; accumulate BN stats.
// root staged in LDS once.
__global__ __launch_bounds__(256) void pre_stats(const float* __restrict__ agg,
                                                 const float* __restrict__ x,
                                                 const float* __restrict__ root,
                                                 const float* __restrict__ bias,
                                                 float* __restrict__ pre,
                                                 float* __restrict__ stats,
                                                 int in, int inshift) {
    __shared__ float rs[64 * 65];      // [i][o] padded row 64->65 (16.6 KB max)
    __shared__ float xs[4][64];
    __shared__ float lsum[64], lsq[64];
    const int o = threadIdx.x & 63, nl = threadIdx.x >> 6;
    if (threadIdx.x < 64) { lsum[threadIdx.x] = 0.f; lsq[threadIdx.x] = 0.f; }
    for (int idx = threadIdx.x; idx < (in << 6); idx += 256)
        rs[(idx >> 6) * 65 + (idx & 63)] = root[idx];
    const float bo = bias[o];
    for (int n0 = blockIdx.x * 4; n0 < N_NODES; n0 += gridDim.x * 4) {
        __syncthreads();
        for (int idx = threadIdx.x; idx < (4 << inshift); idx += 256) {
            int r = idx >> inshift, i = idx & (in - 1);
            if (n0 + r < N_NODES) xs[r][i] = x[(size_t)(n0 + r) * in + i];
        }
        __syncthreads();
        int n = n0 + nl;
        if (n < N_NODES) {
            float acc = agg[(size_t)n * 64 + o] + bo;
#pragma unroll 8
            for (int i = 0; i < in; i++) acc += xs[nl][i] * rs[i * 65 + o];
            pre[(size_t)n * 64 + o] = acc;
            atomicAdd(&lsum[o], acc);
            atomicAdd(&lsq[o], acc * acc);
        }
    }
    __syncthreads();
    if (threadIdx.x < 64) {
        atomicAdd(&stats[threadIdx.x], lsum[threadIdx.x]);
        atomicAdd(&stats[64 + threadIdx.x], lsq[threadIdx.x]);
    }
}

// ---------------------------------------------------------------------------
// BN (batch stats, biased var) + ReLU. Zeroes pre(=agg) after its single read.
// mode 0: store xn (f32) + xf (f16). mode 1: segment-max pool.
__global__ __launch_bounds__(256) void bn_apply(float* __restrict__ pre,
                                                const float* __restrict__ stats,
                                                const float* __restrict__ gamma,
                                                const float* __restrict__ beta,
                                                float* __restrict__ xn,
                                                f16* __restrict__ xfo,
                                                const int* __restrict__ batch,
                                                float* __restrict__ pooled,
                                                int mode) {
    int idx = blockIdx.x * 256 + threadIdx.x;
    if (idx >= N_NODES * 64) return;
    const int o = idx & 63, n = idx >> 6;
    const float inv = 1.f / (float)N_NODES;
    float mu = stats[o] * inv;
    float var = stats[64 + o] * inv - mu * mu;
    float sc = gamma[o] * rsqrtf(var + EPS);
    float sh = beta[o] - mu * sc;
    float p = pre[idx];
    pre[idx] = 0.f;                     // agg zeroed for the next layer's fused
    float v = fmaxf(p * sc + sh, 0.f);
    if (mode == 0) { xn[idx] = v; xfo[idx] = (f16)v; }
    else atomicMax((int*)&pooled[(size_t)batch[n] * 64 + o], __float_as_int(v));
}

// ---------------------------------------------------------------------------
// out[g] = pp_b2 + relu(cat(pooled[g],u[g]) @ pp_w1 + pp_b1) @ pp_w2
__global__ __launch_bounds__(64) void final_mlp(const float* __restrict__ pooled,
                                                const float* __restrict__ u,
                                                const float* __restrict__ w1,
                                                const float* __restrict__ b1,
                                                const float* __restrict__ w2,
                                                const float* __restrict__ b2,
                                                float* __restrict__ out) {
    const int g = blockIdx.x, t = threadIdx.x;
    float acc = b1[t];
#pragma unroll 8
    for (int i = 0; i < 64; i++) acc += pooled[g * 64 + i] * w1[i * 64 + t];
#pragma unroll
    for (int j = 0; j < GIN; j++) acc += u[g * GIN + j] * w1[(64 + j) * 64 + t];
    float hv = fmaxf(acc, 0.f) * w2[t];
#pragma unroll
    for (int off = 32; off > 0; off >>= 1) hv += __shfl_down(hv, off, 64);
    if (t == 0) out[g] = hv + b2[0];
}

// ---------------------------------------------------------------------------
extern "C" void kernel_launch(void* const* d_in, const int* in_sizes, int n_in,
                              void* d_out, int out_size, void* d_ws, size_t ws_size,
                              hipStream_t stream) {
    const float* x0      = (const float*)d_in[0];
    const int*   ei      = (const int*)d_in[1];
    const int*   src     = ei;
    const int*   dst     = ei + N_EDGES;
    const float* ea      = (const float*)d_in[2];
    const int*   batch   = (const int*)d_in[3];
    const float* u       = (const float*)d_in[4];
    const float* e0w1    = (const float*)d_in[5];
    const float* e0b1    = (const float*)d_in[6];
    const float* e0w2    = (const float*)d_in[7];
    const float* e0b2    = (const float*)d_in[8];
    const float* root0   = (const float*)d_in[9];
    const float* bias0   = (const float*)d_in[10];
    const float* gamma0  = (const float*)d_in[11];
    const float* beta0   = (const float*)d_in[12];
    const float* ew1     = (const float*)d_in[13];
    const float* eb1     = (const float*)d_in[14];
    const float* ew2     = (const float*)d_in[15];
    const float* eb2     = (const float*)d_in[16];
    const float* rootl   = (const float*)d_in[17];
    const float* biasl   = (const float*)d_in[18];
    const float* gammal  = (const float*)d_in[19];
    const float* betal   = (const float*)d_in[20];
    const float* pp_w1   = (const float*)d_in[21];
    const float* pp_b1   = (const float*)d_in[22];
    const float* pp_w2   = (const float*)d_in[23];
    const float* pp_b2   = (const float*)d_in[24];

    float* ws = (float*)d_ws;
    size_t off = 0;
    f16*   htp    = (f16*)(ws + off); off += 4 * HTSTR / 2;        // 51.2 MB
    f16*   xf     = (f16*)(ws + off); off += (size_t)N_NODES * 64 / 2;
    f16*   Bg2    = (f16*)(ws + off); off += 4 * BGSTR / 2;        // 4.2 MB
    float* agg    = ws + off; off += (size_t)N_NODES * 64;
    float* xa     = ws + off; off += (size_t)N_NODES * 64;
    float* xb     = ws + off; off += (size_t)N_NODES * 64;
    float* stats  = ws + off; off += 4 * 128 + 64;
    float* pooled = ws + off; off += (size_t)NG * 64;
    int*   row_ptr = (int*)(ws + off); off += 10008;
    int*   cursor  = (int*)(ws + off); off += 10000;
    int*   cnt     = (int*)(ws + off); off += 10000;
    int*   eix     = (int*)(ws + off); off += N_EDGES;
    int*   vn_node = (int*)(ws + off); off += NVMAX + 12;
    int*   vn_rb   = (int*)(ws + off); off += NVMAX + 12;
    int*   nvp     = (int*)(ws + off); off += 8;

    const int eblocks = (N_EDGES + 255) / 256;               // 196
    const int hblocks = (N_EDGES + 127) / 128;               // 391
    const int bblocks = ((8256 << 6) + 255) / 256;           // 2064
    const int fblocks = (NVMAX + BV - 1) / BV;               // 782
    const int ablocks = (N_NODES * 64 + 255) / 256;

    // ---- head: layer-independent work, once
    hipMemsetAsync(pooled, 0, (size_t)NG * 64 * 4, stream);
    hipMemsetAsync(agg, 0, (size_t)N_NODES * 64 * 4, stream);
    hipMemsetAsync(stats, 0, 4 * 128 * 4, stream);
    hipMemsetAsync(cnt, 0, N_NODES * 4, stream);
    csr_count<<<eblocks, 256, 0, stream>>>(src, cnt);
    csr_scan<<<1, 256, 0, stream>>>(cnt, row_ptr, cursor, vn_node, vn_rb, nvp);
    csr_fill<<<eblocks, 256, 0, stream>>>(src, cursor, eix);
    ht_kernel<<<dim3(hblocks, 4), 256, 0, stream>>>(ea, e0w1, e0b1, ew1, eb1, htp);
    bconv<<<dim3(bblocks, 4), 256, 0, stream>>>(e0w2, e0b2, ew2, eb2, Bg2);
    xconv<<<(N_NODES * IN0 + 255) / 256, 256, 0, stream>>>(x0, xf, N_NODES * IN0);

    struct Layer {
        const float *root, *bias, *gamma, *beta, *xin;
        float* xout; int in, inshift, mode;
    };
    Layer L[4];
    L[0] = {root0, bias0, gamma0, beta0, x0, xa, IN0, 5, 0};
    for (int l = 0; l < 3; l++) {
        const float* xin  = (l == 0) ? xa : ((l == 1) ? xb : xa);
        float*       xout = (l == 0) ? xb : ((l == 1) ? xa : nullptr);
        L[l + 1] = {rootl + (size_t)l * HID * HID, biasl + (size_t)l * HID,
                    gammal + (size_t)l * HID, betal + (size_t)l * HID,
                    xin, xout, HID, 6, (l == 2) ? 1 : 0};
    }

    // ---- per-layer critical path: fused -> pre_stats -> bn_apply
    for (int l = 0; l < 4; l++) {
        const Layer& P = L[l];
        fused_msg2<<<fblocks, 512, 0, stream>>>(htp + (size_t)l * HTSTR, xf,
                                                Bg2 + (size_t)l * BGSTR, eix,
                                                row_ptr, vn_node, vn_rb, dst,
                                                agg, nvp, P.inshift);
        pre_stats<<<512, 256, 0, stream>>>(agg, P.xin, P.root, P.bias, agg,
                                           stats + l * 128, P.in, P.inshift);
        bn_apply<<<ablocks, 256, 0, stream>>>(agg, stats + l * 128, P.gamma,
                                              P.beta, P.xout, xf, batch, pooled,
                                              P.mode);
    }
    final_mlp<<<NG, 64, 0, stream>>>(pooled, u, pp_w1, pp_b1, pp_w2, pp_b2,
                                     (float*)d_out);
}